// Round 8
// baseline (655.291 us; speedup 1.0000x reference)
//
#include <hip/hip_runtime.h>
#include <math.h>

#define D_DIM 4096
#define E_DIM 64
#define KTOP 8
#define TAU 2e-4f     // ambiguity threshold: ~66 sigma of split-bf16 GEMM error (~3e-6 RMS)
#define BM 32         // tokens per block (main) -> grid 512 = 2+ blocks/CU resident
#define BKT 32        // k per tile
#define NT (D_DIM / BKT)   // 128 tiles

// workspace layout (bytes)
#define WS_CNT 0
#define WS_LIST 1024
#define WS_IMG 66560  // 1024 + 64KB list (room for ALL tokens); 16B aligned

typedef __attribute__((ext_vector_type(8))) short bf16x8;
typedef __attribute__((ext_vector_type(4))) float f32x4;

#define MFMA(a, b, c) __builtin_amdgcn_mfma_f32_16x16x32_bf16(a, b, c, 0, 0, 0)

__device__ inline unsigned short bf16_rne(float x) {
    unsigned int b = __float_as_uint(x);
    return (unsigned short)((b + 0x7FFFu + ((b >> 16) & 1u)) >> 16);
}

// ---- preconvert weights: Wr||Wn -> hi/lo bf16 image, fragment-linear per k-tile ----
// image (ushort idx): tile kt: hi at kt*8192 + koff*1024 + col*8 + j ; lo at +4096
__global__ __launch_bounds__(256)
void preconv(const float* __restrict__ Wr, const float* __restrict__ Wn,
             unsigned short* __restrict__ img, unsigned int* __restrict__ cnt)
{
    if (blockIdx.x == 0 && threadIdx.x == 0) *cnt = 0u;   // fused zero_cnt
    int t = blockIdx.x * 256 + threadIdx.x;      // 0..524287
    int kt = t >> 12, rem = t & 4095;
    int koff = rem >> 10, colj = rem & 1023;
    int col = colj >> 3, j = colj & 7;
    int k = kt * 32 + koff * 8 + j;
    float x = (col < E_DIM) ? Wr[(size_t)col * D_DIM + k]
                            : Wn[(size_t)(col - E_DIM) * D_DIM + k];
    unsigned short h = bf16_rne(x);
    float hf = __uint_as_float((unsigned int)h << 16);
    float r = x - hf;                             // exact (Sterbenz)
    unsigned short l = bf16_rne(r);
    img[(size_t)kt * 8192 + koff * 1024 + colj] = h;
    img[(size_t)kt * 8192 + 4096 + koff * 1024 + colj] = l;
}

// ---- split 8 fp32 -> hi/lo bf16x8 via v_cvt_pk_bf16_f32 (RNE) ----
__device__ inline void split8(float4 p, float4 q, bf16x8& h8, bf16x8& l8) {
    float xx[8] = {p.x, p.y, p.z, p.w, q.x, q.y, q.z, q.w};
    union { unsigned int w[4]; bf16x8 v; } H, L;
    #pragma unroll
    for (int i = 0; i < 4; ++i) {
        float a = xx[2 * i], b = xx[2 * i + 1];
        unsigned int hw;
        asm("v_cvt_pk_bf16_f32 %0, %1, %2" : "=v"(hw) : "v"(a), "v"(b));
        float ha = __uint_as_float(hw << 16);
        float hb = __uint_as_float(hw & 0xFFFF0000u);
        float ra = a - ha, rb = b - hb;           // exact residuals
        unsigned int lw;
        asm("v_cvt_pk_bf16_f32 %0, %1, %2" : "=v"(lw) : "v"(ra), "v"(rb));
        H.w[i] = hw; L.w[i] = lw;
    }
    h8 = H.v; l8 = L.v;
}

// ---- main: split-bf16 MFMA GEMM + epilogue + flagging ----
// 4 waves: wr = rowgroup (16 tokens), wc = colgroup (64 cols). 4 blocks/CU.
__global__ __launch_bounds__(256, 4)
void router_main(const float* __restrict__ mh,
                 const unsigned short* __restrict__ Wimg,
                 const float* __restrict__ br, const float* __restrict__ bn,
                 const float* __restrict__ eps,
                 float* __restrict__ out_probs, float* __restrict__ out_idx,
                 unsigned int* __restrict__ cnt, int* __restrict__ list)
{
    extern __shared__ char smem[];
    unsigned short* Bb = (unsigned short*)smem;   // [2][8192] ushorts (32KB), GEMM phase
    float* zs = (float*)smem;                     // [32][132] overlay, epilogue (16.9KB)

    const int tid  = threadIdx.x;
    const int lane = tid & 63;
    const int wv   = tid >> 6;       // 0..3
    const int wr   = wv >> 1;        // rowgroup 0..1 (16 tokens each)
    const int wc   = wv & 1;         // colgroup 0..1 (64 cols each)
    const int tok0 = blockIdx.x * BM;
    const int rloc = lane & 15;
    const int koff = lane >> 4;      // 0..3

    const float* aptr = mh + (size_t)(tok0 + wr * 16 + rloc) * D_DIM + koff * 8;

    int boff[4];
    #pragma unroll
    for (int fc = 0; fc < 4; ++fc)
        boff[fc] = koff * 1024 + (wc * 64 + fc * 16 + rloc) * 8;

    const int4* gimg = (const int4*)Wimg;   // 1024 int4 per k-tile
    int4* Bb4 = (int4*)Bb;                  // 1024 int4 per buffer

    f32x4 acc[4];
    #pragma unroll
    for (int fc = 0; fc < 4; ++fc) acc[fc] = {0.f, 0.f, 0.f, 0.f};

    auto tile_mfma = [&](const unsigned short* bb, bf16x8 ah, bf16x8 al) {
        bf16x8 bh[4], bl[4];
        #pragma unroll
        for (int fc = 0; fc < 4; ++fc) {
            bh[fc] = *(const bf16x8*)(bb + boff[fc]);
            bl[fc] = *(const bf16x8*)(bb + 4096 + boff[fc]);
        }
        #pragma unroll
        for (int fc = 0; fc < 4; ++fc) {
            acc[fc] = MFMA(ah, bh[fc], acc[fc]);
            acc[fc] = MFMA(al, bh[fc], acc[fc]);
            acc[fc] = MFMA(ah, bl[fc], acc[fc]);
        }
    };

    // prologue: stage B tile0 direct; preload B tile1 regs; preload A tiles 0,1
    #pragma unroll
    for (int q = 0; q < 4; ++q)
        Bb4[q * 256 + tid] = gimg[q * 256 + tid];
    int4 p1[4], p2[4];
    #pragma unroll
    for (int q = 0; q < 4; ++q) p1[q] = gimg[1024 + q * 256 + tid];  // B tile 1
    float4 a0A = *(const float4*)(aptr + 0),  a1A = *(const float4*)(aptr + 4);
    float4 a0B = *(const float4*)(aptr + 32), a1B = *(const float4*)(aptr + 36);

    for (int kt = 0; kt < NT; kt += 2) {
        // ---- EVEN tile kt: A in a*A, B in Bb[0] ----
        if (kt + 2 < NT) {  // issue B(kt+2), consumed end of ODD
            #pragma unroll
            for (int q = 0; q < 4; ++q)
                p2[q] = gimg[(size_t)(kt + 2) * 1024 + q * 256 + tid];
        }
        __syncthreads();                          // Bb[0] (tile kt) visible
        {
            bf16x8 ah, al;
            split8(a0A, a1A, ah, al);
            if (kt + 2 < NT) {                    // A 2-deep prefetch
                a0A = *(const float4*)(aptr + (kt + 2) * 32);
                a1A = *(const float4*)(aptr + (kt + 2) * 32 + 4);
            }
            tile_mfma(Bb, ah, al);
        }
        if (kt + 1 < NT) {                        // write B(kt+1) -> Bb[1]
            #pragma unroll
            for (int q = 0; q < 4; ++q) Bb4[1024 + q * 256 + tid] = p1[q];
        }

        // ---- ODD tile kt+1: A in a*B, B in Bb[1] ----
        if (kt + 3 < NT) {  // issue B(kt+3), consumed end of next EVEN
            #pragma unroll
            for (int q = 0; q < 4; ++q)
                p1[q] = gimg[(size_t)(kt + 3) * 1024 + q * 256 + tid];
        }
        __syncthreads();                          // Bb[1] (tile kt+1) visible
        {
            bf16x8 ah, al;
            split8(a0B, a1B, ah, al);
            if (kt + 3 < NT) {
                a0B = *(const float4*)(aptr + (kt + 3) * 32);
                a1B = *(const float4*)(aptr + (kt + 3) * 32 + 4);
            }
            tile_mfma(Bb + 8192, ah, al);
        }
        if (kt + 2 < NT) {                        // write B(kt+2) -> Bb[0]
            #pragma unroll
            for (int q = 0; q < 4; ++q) Bb4[q * 256 + tid] = p2[q];
        }
    }
    __syncthreads();   // all ds_reads done before zs overlays Bb

    // acc -> zs (+bias). C-layout: col=lane&15, row=(lane>>4)*4+reg (m89-verified)
    #pragma unroll
    for (int fc = 0; fc < 4; ++fc) {
        const int col = wc * 64 + fc * 16 + rloc;
        const float bias = (col < E_DIM) ? br[col] : bn[col - E_DIM];
        #pragma unroll
        for (int rg = 0; rg < 4; ++rg) {
            const int row = wr * 16 + koff * 4 + rg;
            zs[row * 132 + col] = acc[fc][rg] + bias;
        }
    }
    __syncthreads();

    // noisy logits, in-place into route half of zs (each octet owned by one thread)
    {
        const int t  = tid >> 3;                 // 0..31
        const int e0 = (tid & 7) << 3;
        const float* ep = eps + (size_t)(tok0 + t) * E_DIM + e0;
        #pragma unroll
        for (int j = 0; j < 8; ++j) {
            float zr = zs[t * 132 + e0 + j];
            float zn = zs[t * 132 + 64 + e0 + j];
            float sp = fmaxf(zn, 0.f) + log1pf(expf(-fabsf(zn)));
            zs[t * 132 + e0 + j] = zr + ep[j] * sp;
        }
    }
    __syncthreads();

    // top-8 (+9th for gap) + masked softmax: wave wv handles tokens wv*8..wv*8+7
    for (int tk = 0; tk < 8; ++tk) {
        int t = wv * 8 + tk;
        float v0 = zs[t * 132 + lane];
        float v  = v0;
        float m0 = 0.f, denom = 0.f, prev = 0.f, mingap = INFINITY;
        bool selected = false;
        int rankedIdx = 0;
        #pragma unroll
        for (int k = 0; k < KTOP + 1; ++k) {
            float mv = v; int mi = lane;
            #pragma unroll
            for (int off = 32; off > 0; off >>= 1) {
                float ov = __shfl_xor(mv, off);
                int   oi = __shfl_xor(mi, off);
                if (ov > mv || (ov == mv && oi < mi)) { mv = ov; mi = oi; }
            }
            if (k == 0) m0 = mv; else mingap = fminf(mingap, prev - mv);
            prev = mv;
            if (k < KTOP) {
                denom += expf(mv - m0);
                if (lane == mi) { selected = true; v = -INFINITY; }
                if (lane == k) rankedIdx = mi;
            }
        }
        float p = selected ? expf(v0 - m0) / denom : 0.f;
        size_t tg = (size_t)(tok0 + t);
        out_probs[tg * E_DIM + lane] = p;
        if (lane < KTOP) out_idx[tg * KTOP + lane] = (float)rankedIdx;
        if (mingap < TAU && lane == 0) {
            unsigned int wpos = atomicAdd(cnt, 1u);
            list[wpos] = (int)tg;
        }
    }
}

// ---- fp64 exact recompute for flagged tokens: 1 block/token ----
__global__ __launch_bounds__(256)
void refine_fp64(const float* __restrict__ mh,
                 const float* __restrict__ Wr, const float* __restrict__ br,
                 const float* __restrict__ Wn, const float* __restrict__ bn,
                 const float* __restrict__ eps,
                 float* __restrict__ out_probs, float* __restrict__ out_idx,
                 const unsigned int* __restrict__ cnt, const int* __restrict__ list)
{
    __shared__ double xs[D_DIM];   // 32KB
    __shared__ double red[128];
    const unsigned int n = *cnt;
    const int tid  = threadIdx.x;
    const int lane = tid & 63;
    const int wv   = tid >> 6;     // 0..3

    for (unsigned int i = blockIdx.x; i < n; i += gridDim.x) {
        const int tok = list[i];
        for (int k = tid * 4; k < D_DIM; k += 1024) {
            float4 xv = *(const float4*)(mh + (size_t)tok * D_DIM + k);
            xs[k]     = (double)xv.x; xs[k + 1] = (double)xv.y;
            xs[k + 2] = (double)xv.z; xs[k + 3] = (double)xv.w;
        }
        __syncthreads();

        for (int r = 0; r < 32; ++r) {
            const int row = wv * 32 + r;
            const float* wp = (row < E_DIM) ? (Wr + (size_t)row * D_DIM)
                                            : (Wn + (size_t)(row - E_DIM) * D_DIM);
            double s0 = 0.0, s1 = 0.0, s2 = 0.0, s3 = 0.0;
            #pragma unroll 4
            for (int k = lane * 4; k < D_DIM; k += 256) {
                float4 w4 = *(const float4*)(wp + k);
                s0 += xs[k]     * (double)w4.x;
                s1 += xs[k + 1] * (double)w4.y;
                s2 += xs[k + 2] * (double)w4.z;
                s3 += xs[k + 3] * (double)w4.w;
            }
            double s = (s0 + s1) + (s2 + s3);
            #pragma unroll
            for (int off = 32; off > 0; off >>= 1) s += __shfl_xor(s, off);
            if (lane == 0) red[row] = s;
        }
        __syncthreads();

        if (wv == 0) {   // epilogue: lane = expert
            double zr = red[lane] + (double)br[lane];
            double zn = red[E_DIM + lane] + (double)bn[lane];
            double sp = fmax(zn, 0.0) + log1p(exp(-fabs(zn)));
            double nl = zr + (double)eps[(size_t)tok * E_DIM + lane] * sp;
            double v = nl, m0 = 0.0, denom = 0.0;
            bool selected = false;
            int rankedIdx = 0;
            #pragma unroll
            for (int k = 0; k < KTOP; ++k) {
                double mv = v; int mi = lane;
                #pragma unroll
                for (int off = 32; off > 0; off >>= 1) {
                    double ov = __shfl_xor(mv, off);
                    int    oi = __shfl_xor(mi, off);
                    if (ov > mv || (ov == mv && oi < mi)) { mv = ov; mi = oi; }
                }
                if (k == 0) m0 = mv;
                denom += exp(mv - m0);
                if (lane == mi) { selected = true; v = -INFINITY; }
                if (lane == k) rankedIdx = mi;
            }
            float p = selected ? (float)(exp(nl - m0) / denom) : 0.f;
            out_probs[(size_t)tok * E_DIM + lane] = p;
            if (lane < KTOP) out_idx[(size_t)tok * KTOP + lane] = (float)rankedIdx;
        }
        __syncthreads();   // xs reused next iteration
    }
}

extern "C" void kernel_launch(void* const* d_in, const int* in_sizes, int n_in,
                              void* d_out, int out_size, void* d_ws, size_t ws_size,
                              hipStream_t stream) {
    const float* mh  = (const float*)d_in[0];
    const float* Wr  = (const float*)d_in[1];
    const float* br  = (const float*)d_in[2];
    const float* Wn  = (const float*)d_in[3];
    const float* bn  = (const float*)d_in[4];
    const float* eps = (const float*)d_in[5];

    const int ntok = in_sizes[0] / D_DIM;                     // 16384
    float* out_probs = (float*)d_out;                         // [ntok][64]
    float* out_idx   = (float*)d_out + (size_t)ntok * E_DIM;  // [ntok][8] as float

    unsigned int* cnt = (unsigned int*)d_ws;
    int* list = (int*)((char*)d_ws + WS_LIST);
    unsigned short* img = (unsigned short*)((char*)d_ws + WS_IMG);

    hipLaunchKernelGGL(preconv, dim3(2048), dim3(256), 0, stream, Wr, Wn, img, cnt);
    hipLaunchKernelGGL(router_main, dim3(ntok / BM), dim3(256), 32768, stream,
                       mh, img, br, bn, eps, out_probs, out_idx, cnt, list);
    hipLaunchKernelGGL(refine_fp64, dim3(1024), dim3(256), 0, stream,
                       mh, Wr, br, Wn, bn, eps, out_probs, out_idx, cnt, list);
}

// Round 10
// 650.722 us; speedup vs baseline: 1.0070x; 1.0070x over previous
//
#include <hip/hip_runtime.h>
#include <math.h>

#define D_DIM 4096
#define E_DIM 64
#define KTOP 8
#define TAU 2e-4f     // ambiguity threshold: ~66 sigma of split-bf16 GEMM error (~3e-6 RMS)
#define BM 32         // tokens per block (main) -> grid 512 = 2+ blocks/CU resident
#define BKT 32        // k per tile
#define NT (D_DIM / BKT)   // 128 tiles

// workspace layout (bytes)
#define WS_CNT 0
#define WS_LIST 1024
#define WS_IMG 66560  // 1024 + 64KB list (room for ALL tokens); 16B aligned

typedef __attribute__((ext_vector_type(8))) short bf16x8;
typedef __attribute__((ext_vector_type(4))) float f32x4;

#define MFMA(a, b, c) __builtin_amdgcn_mfma_f32_16x16x32_bf16(a, b, c, 0, 0, 0)

__device__ inline unsigned short bf16_rne(float x) {
    unsigned int b = __float_as_uint(x);
    return (unsigned short)((b + 0x7FFFu + ((b >> 16) & 1u)) >> 16);
}

// ---- preconvert weights: Wr||Wn -> hi/lo bf16 image, fragment-linear per k-tile ----
// image (ushort idx): tile kt: hi at kt*8192 + koff*1024 + col*8 + j ; lo at +4096
__global__ __launch_bounds__(256)
void preconv(const float* __restrict__ Wr, const float* __restrict__ Wn,
             unsigned short* __restrict__ img, unsigned int* __restrict__ cnt)
{
    if (blockIdx.x == 0 && threadIdx.x == 0) *cnt = 0u;   // fused zero_cnt
    int t = blockIdx.x * 256 + threadIdx.x;      // 0..524287
    int kt = t >> 12, rem = t & 4095;
    int koff = rem >> 10, colj = rem & 1023;
    int col = colj >> 3, j = colj & 7;
    int k = kt * 32 + koff * 8 + j;
    float x = (col < E_DIM) ? Wr[(size_t)col * D_DIM + k]
                            : Wn[(size_t)(col - E_DIM) * D_DIM + k];
    unsigned short h = bf16_rne(x);
    float hf = __uint_as_float((unsigned int)h << 16);
    float r = x - hf;                             // exact (Sterbenz)
    unsigned short l = bf16_rne(r);
    img[(size_t)kt * 8192 + koff * 1024 + colj] = h;
    img[(size_t)kt * 8192 + 4096 + koff * 1024 + colj] = l;
}

// ---- split 8 fp32 -> hi/lo bf16x8 via v_cvt_pk_bf16_f32 (RNE) ----
__device__ inline void split8(float4 p, float4 q, bf16x8& h8, bf16x8& l8) {
    float xx[8] = {p.x, p.y, p.z, p.w, q.x, q.y, q.z, q.w};
    union { unsigned int w[4]; bf16x8 v; } H, L;
    #pragma unroll
    for (int i = 0; i < 4; ++i) {
        float a = xx[2 * i], b = xx[2 * i + 1];
        unsigned int hw;
        asm("v_cvt_pk_bf16_f32 %0, %1, %2" : "=v"(hw) : "v"(a), "v"(b));
        float ha = __uint_as_float(hw << 16);
        float hb = __uint_as_float(hw & 0xFFFF0000u);
        float ra = a - ha, rb = b - hb;           // exact residuals
        unsigned int lw;
        asm("v_cvt_pk_bf16_f32 %0, %1, %2" : "=v"(lw) : "v"(ra), "v"(rb));
        H.w[i] = hw; L.w[i] = lw;
    }
    h8 = H.v; l8 = L.v;
}

// ---- main: split-bf16 MFMA GEMM + epilogue + flagging ----
// 4 waves: wr = rowgroup (16 tokens), wc = colgroup (64 cols).
// __launch_bounds__(256,2): VGPR cap 256 — round 8's (256,4) capped at 128 and
// spilled the staging regs to scratch (WRITE_SIZE 682MB). Do NOT raise again.
__global__ __launch_bounds__(256, 2)
void router_main(const float* __restrict__ mh,
                 const unsigned short* __restrict__ Wimg,
                 const float* __restrict__ br, const float* __restrict__ bn,
                 const float* __restrict__ eps,
                 float* __restrict__ out_probs, float* __restrict__ out_idx,
                 unsigned int* __restrict__ cnt, int* __restrict__ list)
{
    extern __shared__ char smem[];
    unsigned short* Bb = (unsigned short*)smem;   // [2][8192] ushorts (32KB), GEMM phase
    float* zs = (float*)smem;                     // [32][132] overlay, epilogue (16.9KB)

    const int tid  = threadIdx.x;
    const int lane = tid & 63;
    const int wv   = tid >> 6;       // 0..3
    const int wr   = wv >> 1;        // rowgroup 0..1 (16 tokens each)
    const int wc   = wv & 1;         // colgroup 0..1 (64 cols each)
    const int tok0 = blockIdx.x * BM;
    const int rloc = lane & 15;
    const int koff = lane >> 4;      // 0..3

    const float* aptr = mh + (size_t)(tok0 + wr * 16 + rloc) * D_DIM + koff * 8;

    int boff[4];
    #pragma unroll
    for (int fc = 0; fc < 4; ++fc)
        boff[fc] = koff * 1024 + (wc * 64 + fc * 16 + rloc) * 8;

    const int4* gimg = (const int4*)Wimg;   // 1024 int4 per k-tile
    int4* Bb4 = (int4*)Bb;                  // 1024 int4 per buffer

    f32x4 acc[4];
    #pragma unroll
    for (int fc = 0; fc < 4; ++fc) acc[fc] = {0.f, 0.f, 0.f, 0.f};

    auto tile_mfma = [&](const unsigned short* bb, bf16x8 ah, bf16x8 al) {
        bf16x8 bh[4], bl[4];
        #pragma unroll
        for (int fc = 0; fc < 4; ++fc) {
            bh[fc] = *(const bf16x8*)(bb + boff[fc]);
            bl[fc] = *(const bf16x8*)(bb + 4096 + boff[fc]);
        }
        #pragma unroll
        for (int fc = 0; fc < 4; ++fc) {
            acc[fc] = MFMA(ah, bh[fc], acc[fc]);
            acc[fc] = MFMA(al, bh[fc], acc[fc]);
            acc[fc] = MFMA(ah, bl[fc], acc[fc]);
        }
    };

    // prologue: stage B tile0 direct; preload B tile1 regs; preload A tiles 0,1
    #pragma unroll
    for (int q = 0; q < 4; ++q)
        Bb4[q * 256 + tid] = gimg[q * 256 + tid];
    int4 p1[4], p2[4];
    #pragma unroll
    for (int q = 0; q < 4; ++q) p1[q] = gimg[1024 + q * 256 + tid];  // B tile 1
    float4 a0A = *(const float4*)(aptr + 0),  a1A = *(const float4*)(aptr + 4);
    float4 a0B = *(const float4*)(aptr + 32), a1B = *(const float4*)(aptr + 36);

    for (int kt = 0; kt < NT; kt += 2) {
        // ---- EVEN tile kt: A in a*A, B in Bb[0] ----
        if (kt + 2 < NT) {  // issue B(kt+2), consumed end of ODD
            #pragma unroll
            for (int q = 0; q < 4; ++q)
                p2[q] = gimg[(size_t)(kt + 2) * 1024 + q * 256 + tid];
        }
        __syncthreads();                          // Bb[0] (tile kt) visible
        {
            bf16x8 ah, al;
            split8(a0A, a1A, ah, al);
            if (kt + 2 < NT) {                    // A 2-deep prefetch
                a0A = *(const float4*)(aptr + (kt + 2) * 32);
                a1A = *(const float4*)(aptr + (kt + 2) * 32 + 4);
            }
            tile_mfma(Bb, ah, al);
        }
        if (kt + 1 < NT) {                        // write B(kt+1) -> Bb[1]
            #pragma unroll
            for (int q = 0; q < 4; ++q) Bb4[1024 + q * 256 + tid] = p1[q];
        }

        // ---- ODD tile kt+1: A in a*B, B in Bb[1] ----
        if (kt + 3 < NT) {  // issue B(kt+3), consumed end of next EVEN
            #pragma unroll
            for (int q = 0; q < 4; ++q)
                p1[q] = gimg[(size_t)(kt + 3) * 1024 + q * 256 + tid];
        }
        __syncthreads();                          // Bb[1] (tile kt+1) visible
        {
            bf16x8 ah, al;
            split8(a0B, a1B, ah, al);
            if (kt + 3 < NT) {
                a0B = *(const float4*)(aptr + (kt + 3) * 32);
                a1B = *(const float4*)(aptr + (kt + 3) * 32 + 4);
            }
            tile_mfma(Bb + 8192, ah, al);
        }
        if (kt + 2 < NT) {                        // write B(kt+2) -> Bb[0]
            #pragma unroll
            for (int q = 0; q < 4; ++q) Bb4[q * 256 + tid] = p2[q];
        }
    }
    __syncthreads();   // all ds_reads done before zs overlays Bb

    // acc -> zs (+bias). C-layout: col=lane&15, row=(lane>>4)*4+reg (m89-verified)
    #pragma unroll
    for (int fc = 0; fc < 4; ++fc) {
        const int col = wc * 64 + fc * 16 + rloc;
        const float bias = (col < E_DIM) ? br[col] : bn[col - E_DIM];
        #pragma unroll
        for (int rg = 0; rg < 4; ++rg) {
            const int row = wr * 16 + koff * 4 + rg;
            zs[row * 132 + col] = acc[fc][rg] + bias;
        }
    }
    __syncthreads();

    // noisy logits, in-place into route half of zs (each octet owned by one thread)
    {
        const int t  = tid >> 3;                 // 0..31
        const int e0 = (tid & 7) << 3;
        const float* ep = eps + (size_t)(tok0 + t) * E_DIM + e0;
        #pragma unroll
        for (int j = 0; j < 8; ++j) {
            float zr = zs[t * 132 + e0 + j];
            float zn = zs[t * 132 + 64 + e0 + j];
            float sp = fmaxf(zn, 0.f) + log1pf(expf(-fabsf(zn)));
            zs[t * 132 + e0 + j] = zr + ep[j] * sp;
        }
    }
    __syncthreads();

    // top-8 (+9th for gap) + masked softmax: wave wv handles tokens wv*8..wv*8+7
    for (int tk = 0; tk < 8; ++tk) {
        int t = wv * 8 + tk;
        float v0 = zs[t * 132 + lane];
        float v  = v0;
        float m0 = 0.f, denom = 0.f, prev = 0.f, mingap = INFINITY;
        bool selected = false;
        int rankedIdx = 0;
        #pragma unroll
        for (int k = 0; k < KTOP + 1; ++k) {
            float mv = v; int mi = lane;
            #pragma unroll
            for (int off = 32; off > 0; off >>= 1) {
                float ov = __shfl_xor(mv, off);
                int   oi = __shfl_xor(mi, off);
                if (ov > mv || (ov == mv && oi < mi)) { mv = ov; mi = oi; }
            }
            if (k == 0) m0 = mv; else mingap = fminf(mingap, prev - mv);
            prev = mv;
            if (k < KTOP) {
                denom += expf(mv - m0);
                if (lane == mi) { selected = true; v = -INFINITY; }
                if (lane == k) rankedIdx = mi;
            }
        }
        float p = selected ? expf(v0 - m0) / denom : 0.f;
        size_t tg = (size_t)(tok0 + t);
        out_probs[tg * E_DIM + lane] = p;
        if (lane < KTOP) out_idx[tg * KTOP + lane] = (float)rankedIdx;
        if (mingap < TAU && lane == 0) {
            unsigned int wpos = atomicAdd(cnt, 1u);
            list[wpos] = (int)tg;
        }
    }
}

// ---- fp64 exact recompute for flagged tokens: 1 block/token ----
__global__ __launch_bounds__(256)
void refine_fp64(const float* __restrict__ mh,
                 const float* __restrict__ Wr, const float* __restrict__ br,
                 const float* __restrict__ Wn, const float* __restrict__ bn,
                 const float* __restrict__ eps,
                 float* __restrict__ out_probs, float* __restrict__ out_idx,
                 const unsigned int* __restrict__ cnt, const int* __restrict__ list)
{
    __shared__ double xs[D_DIM];   // 32KB
    __shared__ double red[128];
    const unsigned int n = *cnt;
    const int tid  = threadIdx.x;
    const int lane = tid & 63;
    const int wv   = tid >> 6;     // 0..3

    for (unsigned int i = blockIdx.x; i < n; i += gridDim.x) {
        const int tok = list[i];
        for (int k = tid * 4; k < D_DIM; k += 1024) {
            float4 xv = *(const float4*)(mh + (size_t)tok * D_DIM + k);
            xs[k]     = (double)xv.x; xs[k + 1] = (double)xv.y;
            xs[k + 2] = (double)xv.z; xs[k + 3] = (double)xv.w;
        }
        __syncthreads();

        for (int r = 0; r < 32; ++r) {
            const int row = wv * 32 + r;
            const float* wp = (row < E_DIM) ? (Wr + (size_t)row * D_DIM)
                                            : (Wn + (size_t)(row - E_DIM) * D_DIM);
            double s0 = 0.0, s1 = 0.0, s2 = 0.0, s3 = 0.0;
            #pragma unroll 4
            for (int k = lane * 4; k < D_DIM; k += 256) {
                float4 w4 = *(const float4*)(wp + k);
                s0 += xs[k]     * (double)w4.x;
                s1 += xs[k + 1] * (double)w4.y;
                s2 += xs[k + 2] * (double)w4.z;
                s3 += xs[k + 3] * (double)w4.w;
            }
            double s = (s0 + s1) + (s2 + s3);
            #pragma unroll
            for (int off = 32; off > 0; off >>= 1) s += __shfl_xor(s, off);
            if (lane == 0) red[row] = s;
        }
        __syncthreads();

        if (wv == 0) {   // epilogue: lane = expert
            double zr = red[lane] + (double)br[lane];
            double zn = red[E_DIM + lane] + (double)bn[lane];
            double sp = fmax(zn, 0.0) + log1p(exp(-fabs(zn)));
            double nl = zr + (double)eps[(size_t)tok * E_DIM + lane] * sp;
            double v = nl, m0 = 0.0, denom = 0.0;
            bool selected = false;
            int rankedIdx = 0;
            #pragma unroll
            for (int k = 0; k < KTOP; ++k) {
                double mv = v; int mi = lane;
                #pragma unroll
                for (int off = 32; off > 0; off >>= 1) {
                    double ov = __shfl_xor(mv, off);
                    int    oi = __shfl_xor(mi, off);
                    if (ov > mv || (ov == mv && oi < mi)) { mv = ov; mi = oi; }
                }
                if (k == 0) m0 = mv;
                denom += exp(mv - m0);
                if (lane == mi) { selected = true; v = -INFINITY; }
                if (lane == k) rankedIdx = mi;
            }
            float p = selected ? (float)(exp(nl - m0) / denom) : 0.f;
            out_probs[(size_t)tok * E_DIM + lane] = p;
            if (lane < KTOP) out_idx[(size_t)tok * KTOP + lane] = (float)rankedIdx;
        }
        __syncthreads();   // xs reused next iteration
    }
}

extern "C" void kernel_launch(void* const* d_in, const int* in_sizes, int n_in,
                              void* d_out, int out_size, void* d_ws, size_t ws_size,
                              hipStream_t stream) {
    const float* mh  = (const float*)d_in[0];
    const float* Wr  = (const float*)d_in[1];
    const float* br  = (const float*)d_in[2];
    const float* Wn  = (const float*)d_in[3];
    const float* bn  = (const float*)d_in[4];
    const float* eps = (const float*)d_in[5];

    const int ntok = in_sizes[0] / D_DIM;                     // 16384
    float* out_probs = (float*)d_out;                         // [ntok][64]
    float* out_idx   = (float*)d_out + (size_t)ntok * E_DIM;  // [ntok][8] as float

    unsigned int* cnt = (unsigned int*)d_ws;
    int* list = (int*)((char*)d_ws + WS_LIST);
    unsigned short* img = (unsigned short*)((char*)d_ws + WS_IMG);

    hipLaunchKernelGGL(preconv, dim3(2048), dim3(256), 0, stream, Wr, Wn, img, cnt);
    hipLaunchKernelGGL(router_main, dim3(ntok / BM), dim3(256), 32768, stream,
                       mh, img, br, bn, eps, out_probs, out_idx, cnt, list);
    hipLaunchKernelGGL(refine_fp64, dim3(1024), dim3(256), 0, stream,
                       mh, Wr, br, Wn, bn, eps, out_probs, out_idx, cnt, list);
}

// Round 11
// 352.096 us; speedup vs baseline: 1.8611x; 1.8481x over previous
//
#include <hip/hip_runtime.h>
#include <math.h>

#define D_DIM 4096
#define E_DIM 64
#define KTOP 8
#define TAU 2e-4f     // ambiguity threshold: ~66 sigma of split-bf16 GEMM error (~3e-6 RMS)
#define BM 32         // tokens per block (main) -> grid 512 = 2+ blocks/CU resident
#define BKT 32        // k per tile
#define NT (D_DIM / BKT)   // 128 tiles

// workspace layout (bytes)
#define WS_CNT 0
#define WS_LIST 1024
#define WS_IMG 66560  // 1024 + 64KB list (room for ALL tokens); 16B aligned

typedef __attribute__((ext_vector_type(8))) short bf16x8;
typedef __attribute__((ext_vector_type(4))) float f32x4;

#define MFMA(a, b, c) __builtin_amdgcn_mfma_f32_16x16x32_bf16(a, b, c, 0, 0, 0)

__device__ inline unsigned short bf16_rne(float x) {
    unsigned int b = __float_as_uint(x);
    return (unsigned short)((b + 0x7FFFu + ((b >> 16) & 1u)) >> 16);
}

// ---- preconvert weights: Wr||Wn -> hi/lo bf16 image, fragment-linear per k-tile ----
// image (ushort idx): tile kt: hi at kt*8192 + koff*1024 + col*8 + j ; lo at +4096
__global__ __launch_bounds__(256)
void preconv(const float* __restrict__ Wr, const float* __restrict__ Wn,
             unsigned short* __restrict__ img, unsigned int* __restrict__ cnt)
{
    if (blockIdx.x == 0 && threadIdx.x == 0) *cnt = 0u;   // fused zero_cnt
    int t = blockIdx.x * 256 + threadIdx.x;      // 0..524287
    int kt = t >> 12, rem = t & 4095;
    int koff = rem >> 10, colj = rem & 1023;
    int col = colj >> 3, j = colj & 7;
    int k = kt * 32 + koff * 8 + j;
    float x = (col < E_DIM) ? Wr[(size_t)col * D_DIM + k]
                            : Wn[(size_t)(col - E_DIM) * D_DIM + k];
    unsigned short h = bf16_rne(x);
    float hf = __uint_as_float((unsigned int)h << 16);
    float r = x - hf;                             // exact (Sterbenz)
    unsigned short l = bf16_rne(r);
    img[(size_t)kt * 8192 + koff * 1024 + colj] = h;
    img[(size_t)kt * 8192 + 4096 + koff * 1024 + colj] = l;
}

// ---- split 8 fp32 -> hi/lo bf16x8 via v_cvt_pk_bf16_f32 (RNE) ----
__device__ inline void split8(float4 p, float4 q, bf16x8& h8, bf16x8& l8) {
    float xx[8] = {p.x, p.y, p.z, p.w, q.x, q.y, q.z, q.w};
    union { unsigned int w[4]; bf16x8 v; } H, L;
    #pragma unroll
    for (int i = 0; i < 4; ++i) {
        float a = xx[2 * i], b = xx[2 * i + 1];
        unsigned int hw;
        asm("v_cvt_pk_bf16_f32 %0, %1, %2" : "=v"(hw) : "v"(a), "v"(b));
        float ha = __uint_as_float(hw << 16);
        float hb = __uint_as_float(hw & 0xFFFF0000u);
        float ra = a - ha, rb = b - hb;           // exact residuals
        unsigned int lw;
        asm("v_cvt_pk_bf16_f32 %0, %1, %2" : "=v"(lw) : "v"(ra), "v"(rb));
        H.w[i] = hw; L.w[i] = lw;
    }
    h8 = H.v; l8 = L.v;
}

// ---- main: split-bf16 MFMA GEMM + epilogue + flagging ----
// 4 waves: wr = rowgroup (16 tokens), wc = colgroup (64 cols).
// RULE #20 (r8/r10 post-mortem): B-staging MUST be named scalars, not int4[4]
// arrays — SROA demoted the arrays to scratch (VGPR=40, WRITE_SIZE 660MB of
// scratch spill traffic, 2.3x regression). Named scalars restore registers.
__global__ __launch_bounds__(256, 2)
void router_main(const float* __restrict__ mh,
                 const unsigned short* __restrict__ Wimg,
                 const float* __restrict__ br, const float* __restrict__ bn,
                 const float* __restrict__ eps,
                 float* __restrict__ out_probs, float* __restrict__ out_idx,
                 unsigned int* __restrict__ cnt, int* __restrict__ list)
{
    extern __shared__ char smem[];
    unsigned short* Bb = (unsigned short*)smem;   // [2][8192] ushorts (32KB), GEMM phase
    float* zs = (float*)smem;                     // [32][132] overlay, epilogue (16.9KB)

    const int tid  = threadIdx.x;
    const int lane = tid & 63;
    const int wv   = tid >> 6;       // 0..3
    const int wr   = wv >> 1;        // rowgroup 0..1 (16 tokens each)
    const int wc   = wv & 1;         // colgroup 0..1 (64 cols each)
    const int tok0 = blockIdx.x * BM;
    const int rloc = lane & 15;
    const int koff = lane >> 4;      // 0..3

    const float* aptr = mh + (size_t)(tok0 + wr * 16 + rloc) * D_DIM + koff * 8;

    int boff[4];
    #pragma unroll
    for (int fc = 0; fc < 4; ++fc)
        boff[fc] = koff * 1024 + (wc * 64 + fc * 16 + rloc) * 8;

    const int4* gimg = (const int4*)Wimg;   // 1024 int4 per k-tile
    int4* Bb4 = (int4*)Bb;                  // 1024 int4 per buffer

    f32x4 acc[4];
    #pragma unroll
    for (int fc = 0; fc < 4; ++fc) acc[fc] = {0.f, 0.f, 0.f, 0.f};

    auto tile_mfma = [&](const unsigned short* bb, bf16x8 ah, bf16x8 al) {
        bf16x8 bh[4], bl[4];
        #pragma unroll
        for (int fc = 0; fc < 4; ++fc) {
            bh[fc] = *(const bf16x8*)(bb + boff[fc]);
            bl[fc] = *(const bf16x8*)(bb + 4096 + boff[fc]);
        }
        #pragma unroll
        for (int fc = 0; fc < 4; ++fc) {
            acc[fc] = MFMA(ah, bh[fc], acc[fc]);
            acc[fc] = MFMA(al, bh[fc], acc[fc]);
            acc[fc] = MFMA(ah, bl[fc], acc[fc]);
        }
    };

    // prologue: stage B tile0 direct; preload B tile1 into NAMED scalar regs
    Bb4[tid]       = gimg[tid];
    Bb4[256 + tid] = gimg[256 + tid];
    Bb4[512 + tid] = gimg[512 + tid];
    Bb4[768 + tid] = gimg[768 + tid];
    int4 p1a = gimg[1024 + tid];
    int4 p1b = gimg[1280 + tid];
    int4 p1c = gimg[1536 + tid];
    int4 p1d = gimg[1792 + tid];
    int4 p2a, p2b, p2c, p2d;
    float4 a0A = *(const float4*)(aptr + 0),  a1A = *(const float4*)(aptr + 4);
    float4 a0B = *(const float4*)(aptr + 32), a1B = *(const float4*)(aptr + 36);

    for (int kt = 0; kt < NT; kt += 2) {
        // ---- EVEN tile kt: A in a*A, B in Bb[0] ----
        if (kt + 2 < NT) {  // issue B(kt+2), consumed end of ODD
            const int4* g2 = gimg + (size_t)(kt + 2) * 1024 + tid;
            p2a = g2[0]; p2b = g2[256]; p2c = g2[512]; p2d = g2[768];
        }
        __syncthreads();                          // Bb[0] (tile kt) visible
        {
            bf16x8 ah, al;
            split8(a0A, a1A, ah, al);
            if (kt + 2 < NT) {                    // A 2-deep prefetch
                a0A = *(const float4*)(aptr + (kt + 2) * 32);
                a1A = *(const float4*)(aptr + (kt + 2) * 32 + 4);
            }
            tile_mfma(Bb, ah, al);
        }
        if (kt + 1 < NT) {                        // write B(kt+1) -> Bb[1]
            Bb4[1024 + tid] = p1a;
            Bb4[1280 + tid] = p1b;
            Bb4[1536 + tid] = p1c;
            Bb4[1792 + tid] = p1d;
        }

        // ---- ODD tile kt+1: A in a*B, B in Bb[1] ----
        if (kt + 3 < NT) {  // issue B(kt+3), consumed end of next EVEN
            const int4* g1 = gimg + (size_t)(kt + 3) * 1024 + tid;
            p1a = g1[0]; p1b = g1[256]; p1c = g1[512]; p1d = g1[768];
        }
        __syncthreads();                          // Bb[1] (tile kt+1) visible
        {
            bf16x8 ah, al;
            split8(a0B, a1B, ah, al);
            if (kt + 3 < NT) {
                a0B = *(const float4*)(aptr + (kt + 3) * 32);
                a1B = *(const float4*)(aptr + (kt + 3) * 32 + 4);
            }
            tile_mfma(Bb + 8192, ah, al);
        }
        if (kt + 2 < NT) {                        // write B(kt+2) -> Bb[0]
            Bb4[tid]       = p2a;
            Bb4[256 + tid] = p2b;
            Bb4[512 + tid] = p2c;
            Bb4[768 + tid] = p2d;
        }
    }
    __syncthreads();   // all ds_reads done before zs overlays Bb

    // acc -> zs (+bias). C-layout: col=lane&15, row=(lane>>4)*4+reg (m89-verified)
    #pragma unroll
    for (int fc = 0; fc < 4; ++fc) {
        const int col = wc * 64 + fc * 16 + rloc;
        const float bias = (col < E_DIM) ? br[col] : bn[col - E_DIM];
        #pragma unroll
        for (int rg = 0; rg < 4; ++rg) {
            const int row = wr * 16 + koff * 4 + rg;
            zs[row * 132 + col] = acc[fc][rg] + bias;
        }
    }
    __syncthreads();

    // noisy logits, in-place into route half of zs (each octet owned by one thread)
    {
        const int t  = tid >> 3;                 // 0..31
        const int e0 = (tid & 7) << 3;
        const float* ep = eps + (size_t)(tok0 + t) * E_DIM + e0;
        #pragma unroll
        for (int j = 0; j < 8; ++j) {
            float zr = zs[t * 132 + e0 + j];
            float zn = zs[t * 132 + 64 + e0 + j];
            float sp = fmaxf(zn, 0.f) + log1pf(expf(-fabsf(zn)));
            zs[t * 132 + e0 + j] = zr + ep[j] * sp;
        }
    }
    __syncthreads();

    // top-8 (+9th for gap) + masked softmax: wave wv handles tokens wv*8..wv*8+7
    for (int tk = 0; tk < 8; ++tk) {
        int t = wv * 8 + tk;
        float v0 = zs[t * 132 + lane];
        float v  = v0;
        float m0 = 0.f, denom = 0.f, prev = 0.f, mingap = INFINITY;
        bool selected = false;
        int rankedIdx = 0;
        #pragma unroll
        for (int k = 0; k < KTOP + 1; ++k) {
            float mv = v; int mi = lane;
            #pragma unroll
            for (int off = 32; off > 0; off >>= 1) {
                float ov = __shfl_xor(mv, off);
                int   oi = __shfl_xor(mi, off);
                if (ov > mv || (ov == mv && oi < mi)) { mv = ov; mi = oi; }
            }
            if (k == 0) m0 = mv; else mingap = fminf(mingap, prev - mv);
            prev = mv;
            if (k < KTOP) {
                denom += expf(mv - m0);
                if (lane == mi) { selected = true; v = -INFINITY; }
                if (lane == k) rankedIdx = mi;
            }
        }
        float p = selected ? expf(v0 - m0) / denom : 0.f;
        size_t tg = (size_t)(tok0 + t);
        out_probs[tg * E_DIM + lane] = p;
        if (lane < KTOP) out_idx[tg * KTOP + lane] = (float)rankedIdx;
        if (mingap < TAU && lane == 0) {
            unsigned int wpos = atomicAdd(cnt, 1u);
            list[wpos] = (int)tg;
        }
    }
}

// ---- fp64 exact recompute for flagged tokens: 1 block/token ----
__global__ __launch_bounds__(256)
void refine_fp64(const float* __restrict__ mh,
                 const float* __restrict__ Wr, const float* __restrict__ br,
                 const float* __restrict__ Wn, const float* __restrict__ bn,
                 const float* __restrict__ eps,
                 float* __restrict__ out_probs, float* __restrict__ out_idx,
                 const unsigned int* __restrict__ cnt, const int* __restrict__ list)
{
    __shared__ double xs[D_DIM];   // 32KB
    __shared__ double red[128];
    const unsigned int n = *cnt;
    const int tid  = threadIdx.x;
    const int lane = tid & 63;
    const int wv   = tid >> 6;     // 0..3

    for (unsigned int i = blockIdx.x; i < n; i += gridDim.x) {
        const int tok = list[i];
        for (int k = tid * 4; k < D_DIM; k += 1024) {
            float4 xv = *(const float4*)(mh + (size_t)tok * D_DIM + k);
            xs[k]     = (double)xv.x; xs[k + 1] = (double)xv.y;
            xs[k + 2] = (double)xv.z; xs[k + 3] = (double)xv.w;
        }
        __syncthreads();

        for (int r = 0; r < 32; ++r) {
            const int row = wv * 32 + r;
            const float* wp = (row < E_DIM) ? (Wr + (size_t)row * D_DIM)
                                            : (Wn + (size_t)(row - E_DIM) * D_DIM);
            double s0 = 0.0, s1 = 0.0, s2 = 0.0, s3 = 0.0;
            #pragma unroll 4
            for (int k = lane * 4; k < D_DIM; k += 256) {
                float4 w4 = *(const float4*)(wp + k);
                s0 += xs[k]     * (double)w4.x;
                s1 += xs[k + 1] * (double)w4.y;
                s2 += xs[k + 2] * (double)w4.z;
                s3 += xs[k + 3] * (double)w4.w;
            }
            double s = (s0 + s1) + (s2 + s3);
            #pragma unroll
            for (int off = 32; off > 0; off >>= 1) s += __shfl_xor(s, off);
            if (lane == 0) red[row] = s;
        }
        __syncthreads();

        if (wv == 0) {   // epilogue: lane = expert
            double zr = red[lane] + (double)br[lane];
            double zn = red[E_DIM + lane] + (double)bn[lane];
            double sp = fmax(zn, 0.0) + log1p(exp(-fabs(zn)));
            double nl = zr + (double)eps[(size_t)tok * E_DIM + lane] * sp;
            double v = nl, m0 = 0.0, denom = 0.0;
            bool selected = false;
            int rankedIdx = 0;
            #pragma unroll
            for (int k = 0; k < KTOP; ++k) {
                double mv = v; int mi = lane;
                #pragma unroll
                for (int off = 32; off > 0; off >>= 1) {
                    double ov = __shfl_xor(mv, off);
                    int    oi = __shfl_xor(mi, off);
                    if (ov > mv || (ov == mv && oi < mi)) { mv = ov; mi = oi; }
                }
                if (k == 0) m0 = mv;
                denom += exp(mv - m0);
                if (lane == mi) { selected = true; v = -INFINITY; }
                if (lane == k) rankedIdx = mi;
            }
            float p = selected ? (float)(exp(nl - m0) / denom) : 0.f;
            out_probs[(size_t)tok * E_DIM + lane] = p;
            if (lane < KTOP) out_idx[(size_t)tok * KTOP + lane] = (float)rankedIdx;
        }
        __syncthreads();   // xs reused next iteration
    }
}

extern "C" void kernel_launch(void* const* d_in, const int* in_sizes, int n_in,
                              void* d_out, int out_size, void* d_ws, size_t ws_size,
                              hipStream_t stream) {
    const float* mh  = (const float*)d_in[0];
    const float* Wr  = (const float*)d_in[1];
    const float* br  = (const float*)d_in[2];
    const float* Wn  = (const float*)d_in[3];
    const float* bn  = (const float*)d_in[4];
    const float* eps = (const float*)d_in[5];

    const int ntok = in_sizes[0] / D_DIM;                     // 16384
    float* out_probs = (float*)d_out;                         // [ntok][64]
    float* out_idx   = (float*)d_out + (size_t)ntok * E_DIM;  // [ntok][8] as float

    unsigned int* cnt = (unsigned int*)d_ws;
    int* list = (int*)((char*)d_ws + WS_LIST);
    unsigned short* img = (unsigned short*)((char*)d_ws + WS_IMG);

    hipLaunchKernelGGL(preconv, dim3(2048), dim3(256), 0, stream, Wr, Wn, img, cnt);
    hipLaunchKernelGGL(router_main, dim3(ntok / BM), dim3(256), 32768, stream,
                       mh, img, br, bn, eps, out_probs, out_idx, cnt, list);
    hipLaunchKernelGGL(refine_fp64, dim3(1024), dim3(256), 0, stream,
                       mh, Wr, br, Wn, bn, eps, out_probs, out_idx, cnt, list);
}

// Round 12
// 340.701 us; speedup vs baseline: 1.9234x; 1.0334x over previous
//
#include <hip/hip_runtime.h>
#include <math.h>

#define D_DIM 4096
#define E_DIM 64
#define KTOP 8
#define TAU 2e-4f     // ambiguity threshold: ~66 sigma of split-bf16 GEMM error (~3e-6 RMS)
#define BM 32         // tokens per block; 512 thr -> grid 512 -> 2 blocks/CU = 16 waves/CU
#define BKT 32        // k per tile
#define NT (D_DIM / BKT)   // 128 tiles

// workspace layout (bytes)
#define WS_CNT 0
#define WS_LIST 1024
#define WS_IMG 66560  // 1024 + 64KB list; 16B aligned

typedef __attribute__((ext_vector_type(8))) short bf16x8;
typedef __attribute__((ext_vector_type(4))) float f32x4;

#define MFMA(a, b, c) __builtin_amdgcn_mfma_f32_16x16x32_bf16(a, b, c, 0, 0, 0)

// ---- split 8 fp32 -> hi/lo bf16x8 via v_cvt_pk_bf16_f32 (RNE) ----
__device__ inline void split8(float4 p, float4 q, bf16x8& h8, bf16x8& l8) {
    float xx[8] = {p.x, p.y, p.z, p.w, q.x, q.y, q.z, q.w};
    union { unsigned int w[4]; bf16x8 v; } H, L;
    #pragma unroll
    for (int i = 0; i < 4; ++i) {
        float a = xx[2 * i], b = xx[2 * i + 1];
        unsigned int hw;
        asm("v_cvt_pk_bf16_f32 %0, %1, %2" : "=v"(hw) : "v"(a), "v"(b));
        float ha = __uint_as_float(hw << 16);
        float hb = __uint_as_float(hw & 0xFFFF0000u);
        float ra = a - ha, rb = b - hb;           // exact residuals
        unsigned int lw;
        asm("v_cvt_pk_bf16_f32 %0, %1, %2" : "=v"(lw) : "v"(ra), "v"(rb));
        H.w[i] = hw; L.w[i] = lw;
    }
    h8 = H.v; l8 = L.v;
}

// ---- preconvert weights: Wr||Wn -> hi/lo bf16 image, fragment-linear per k-tile ----
// 8 elements/thread (one col-octet), coalesced bf16x8 stores.
// image (ushort idx): tile kt: hi at kt*8192 + koff*1024 + col*8 + j ; lo at +4096
__global__ __launch_bounds__(256)
void preconv(const float* __restrict__ Wr, const float* __restrict__ Wn,
             unsigned short* __restrict__ img, unsigned int* __restrict__ cnt)
{
    if (blockIdx.x == 0 && threadIdx.x == 0) *cnt = 0u;   // fused zero_cnt
    int t = blockIdx.x * 256 + threadIdx.x;      // 0..65535
    int kt = t >> 9, rem = t & 511;
    int koff = rem >> 7, col = rem & 127;
    int k = kt * 32 + koff * 8;
    const float* base = (col < E_DIM) ? (Wr + (size_t)col * D_DIM)
                                      : (Wn + (size_t)(col - E_DIM) * D_DIM);
    float4 x0 = *(const float4*)(base + k);
    float4 x1 = *(const float4*)(base + k + 4);
    bf16x8 h8, l8;
    split8(x0, x1, h8, l8);                       // RNE, same as router's A-split
    size_t o = (size_t)kt * 8192 + koff * 1024 + col * 8;
    *(bf16x8*)(img + o) = h8;
    *(bf16x8*)(img + o + 4096) = l8;
}

// ---- main: split-bf16 MFMA GEMM + epilogue + flagging ----
// 8 waves: wr = wv>>2 rowgroup (16 tokens), wc = wv&3 colgroup (32 cols).
// RULE #20 (r8/r10): all cross-iteration staging in NAMED scalars — int4[4]
// arrays were demoted to scratch (VGPR=40, WRITE_SIZE 660MB, 2.3x regression).
__global__ __launch_bounds__(512, 2)
void router_main(const float* __restrict__ mh,
                 const unsigned short* __restrict__ Wimg,
                 const float* __restrict__ br, const float* __restrict__ bn,
                 const float* __restrict__ eps,
                 float* __restrict__ out_probs, float* __restrict__ out_idx,
                 unsigned int* __restrict__ cnt, int* __restrict__ list)
{
    extern __shared__ char smem[];
    unsigned short* Bb = (unsigned short*)smem;   // [2][8192] ushorts (32KB), GEMM phase
    float* zs = (float*)smem;                     // [32][132] overlay, epilogue (16.9KB)

    const int tid  = threadIdx.x;
    const int lane = tid & 63;
    const int wv   = tid >> 6;       // 0..7
    const int wr   = wv >> 2;        // rowgroup 0..1 (16 tokens each)
    const int wc   = wv & 3;         // colgroup 0..3 (32 cols each)
    const int tok0 = blockIdx.x * BM;
    const int rloc = lane & 15;
    const int koff = lane >> 4;      // 0..3

    const float* aptr = mh + (size_t)(tok0 + wr * 16 + rloc) * D_DIM + koff * 8;

    const int boff0 = koff * 1024 + (wc * 32 + rloc) * 8;        // col-frag 0
    const int boff1 = boff0 + 16 * 8;                            // col-frag 1

    const int4* gimg = (const int4*)Wimg;   // 1024 int4 per k-tile
    int4* Bb4 = (int4*)Bb;                  // 1024 int4 per buffer

    f32x4 acc0 = {0.f, 0.f, 0.f, 0.f};
    f32x4 acc1 = {0.f, 0.f, 0.f, 0.f};

    auto tile_mfma = [&](const unsigned short* bb, bf16x8 ah, bf16x8 al) {
        bf16x8 bh0 = *(const bf16x8*)(bb + boff0);
        bf16x8 bh1 = *(const bf16x8*)(bb + boff1);
        bf16x8 bl0 = *(const bf16x8*)(bb + 4096 + boff0);
        bf16x8 bl1 = *(const bf16x8*)(bb + 4096 + boff1);
        acc0 = MFMA(ah, bh0, acc0);
        acc0 = MFMA(al, bh0, acc0);
        acc0 = MFMA(ah, bl0, acc0);
        acc1 = MFMA(ah, bh1, acc1);
        acc1 = MFMA(al, bh1, acc1);
        acc1 = MFMA(ah, bl1, acc1);
    };

    // prologue: stage B tile0 direct; preload B tile1 into NAMED scalar regs
    Bb4[tid]       = gimg[tid];
    Bb4[512 + tid] = gimg[512 + tid];
    int4 p1a = gimg[1024 + tid];
    int4 p1b = gimg[1536 + tid];
    int4 p2a, p2b;
    float4 a0A = *(const float4*)(aptr + 0),  a1A = *(const float4*)(aptr + 4);
    float4 a0B = *(const float4*)(aptr + 32), a1B = *(const float4*)(aptr + 36);

    for (int kt = 0; kt < NT; kt += 2) {
        // ---- EVEN tile kt: A in a*A, B in Bb[0] ----
        if (kt + 2 < NT) {  // issue B(kt+2), consumed end of ODD
            const int4* g2 = gimg + (size_t)(kt + 2) * 1024 + tid;
            p2a = g2[0]; p2b = g2[512];
        }
        __syncthreads();                          // Bb[0] (tile kt) visible
        {
            bf16x8 ah, al;
            split8(a0A, a1A, ah, al);
            if (kt + 2 < NT) {                    // A 2-deep prefetch
                a0A = *(const float4*)(aptr + (kt + 2) * 32);
                a1A = *(const float4*)(aptr + (kt + 2) * 32 + 4);
            }
            tile_mfma(Bb, ah, al);
        }
        if (kt + 1 < NT) {                        // write B(kt+1) -> Bb[1]
            Bb4[1024 + tid] = p1a;
            Bb4[1536 + tid] = p1b;
        }

        // ---- ODD tile kt+1: A in a*B, B in Bb[1] ----
        if (kt + 3 < NT) {  // issue B(kt+3), consumed end of next EVEN
            const int4* g1 = gimg + (size_t)(kt + 3) * 1024 + tid;
            p1a = g1[0]; p1b = g1[512];
        }
        __syncthreads();                          // Bb[1] (tile kt+1) visible
        {
            bf16x8 ah, al;
            split8(a0B, a1B, ah, al);
            if (kt + 3 < NT) {
                a0B = *(const float4*)(aptr + (kt + 3) * 32);
                a1B = *(const float4*)(aptr + (kt + 3) * 32 + 4);
            }
            tile_mfma(Bb + 8192, ah, al);
        }
        if (kt + 2 < NT) {                        // write B(kt+2) -> Bb[0]
            Bb4[tid]       = p2a;
            Bb4[512 + tid] = p2b;
        }
    }
    __syncthreads();   // all ds_reads done before zs overlays Bb

    // acc -> zs (+bias). C-layout: col=lane&15, row=(lane>>4)*4+reg (m89-verified)
    {
        const int c0 = wc * 32 + rloc;
        const int c1 = c0 + 16;
        const float bias0 = (c0 < E_DIM) ? br[c0] : bn[c0 - E_DIM];
        const float bias1 = (c1 < E_DIM) ? br[c1] : bn[c1 - E_DIM];
        #pragma unroll
        for (int rg = 0; rg < 4; ++rg) {
            const int row = wr * 16 + koff * 4 + rg;
            zs[row * 132 + c0] = acc0[rg] + bias0;
            zs[row * 132 + c1] = acc1[rg] + bias1;
        }
    }
    __syncthreads();

    // noisy logits, in-place into route half of zs (each quad owned by one thread)
    {
        const int t  = tid >> 4;                 // 0..31
        const int e0 = (tid & 15) << 2;          // 0..60
        float4 ep = *(const float4*)(eps + (size_t)(tok0 + t) * E_DIM + e0);
        float epv[4] = {ep.x, ep.y, ep.z, ep.w};
        #pragma unroll
        for (int j = 0; j < 4; ++j) {
            float zr = zs[t * 132 + e0 + j];
            float zn = zs[t * 132 + 64 + e0 + j];
            float sp = fmaxf(zn, 0.f) + log1pf(expf(-fabsf(zn)));
            zs[t * 132 + e0 + j] = zr + epv[j] * sp;
        }
    }
    __syncthreads();

    // top-8 (+9th for gap) + masked softmax: wave wv handles tokens wv*4..wv*4+3
    for (int tk = 0; tk < 4; ++tk) {
        int t = wv * 4 + tk;
        float v0 = zs[t * 132 + lane];
        float v  = v0;
        float m0 = 0.f, denom = 0.f, prev = 0.f, mingap = INFINITY;
        bool selected = false;
        int rankedIdx = 0;
        #pragma unroll
        for (int k = 0; k < KTOP + 1; ++k) {
            float mv = v; int mi = lane;
            #pragma unroll
            for (int off = 32; off > 0; off >>= 1) {
                float ov = __shfl_xor(mv, off);
                int   oi = __shfl_xor(mi, off);
                if (ov > mv || (ov == mv && oi < mi)) { mv = ov; mi = oi; }
            }
            if (k == 0) m0 = mv; else mingap = fminf(mingap, prev - mv);
            prev = mv;
            if (k < KTOP) {
                denom += expf(mv - m0);
                if (lane == mi) { selected = true; v = -INFINITY; }
                if (lane == k) rankedIdx = mi;
            }
        }
        float p = selected ? expf(v0 - m0) / denom : 0.f;
        size_t tg = (size_t)(tok0 + t);
        out_probs[tg * E_DIM + lane] = p;
        if (lane < KTOP) out_idx[tg * KTOP + lane] = (float)rankedIdx;
        if (mingap < TAU && lane == 0) {
            unsigned int wpos = atomicAdd(cnt, 1u);
            list[wpos] = (int)tg;
        }
    }
}

// ---- fp64 exact recompute for flagged tokens: 1 block/token ----
__global__ __launch_bounds__(256)
void refine_fp64(const float* __restrict__ mh,
                 const float* __restrict__ Wr, const float* __restrict__ br,
                 const float* __restrict__ Wn, const float* __restrict__ bn,
                 const float* __restrict__ eps,
                 float* __restrict__ out_probs, float* __restrict__ out_idx,
                 const unsigned int* __restrict__ cnt, const int* __restrict__ list)
{
    __shared__ double xs[D_DIM];   // 32KB
    __shared__ double red[128];
    const unsigned int n = *cnt;
    const int tid  = threadIdx.x;
    const int lane = tid & 63;
    const int wv   = tid >> 6;     // 0..3

    for (unsigned int i = blockIdx.x; i < n; i += gridDim.x) {
        const int tok = list[i];
        for (int k = tid * 4; k < D_DIM; k += 1024) {
            float4 xv = *(const float4*)(mh + (size_t)tok * D_DIM + k);
            xs[k]     = (double)xv.x; xs[k + 1] = (double)xv.y;
            xs[k + 2] = (double)xv.z; xs[k + 3] = (double)xv.w;
        }
        __syncthreads();

        for (int r = 0; r < 32; ++r) {
            const int row = wv * 32 + r;
            const float* wp = (row < E_DIM) ? (Wr + (size_t)row * D_DIM)
                                            : (Wn + (size_t)(row - E_DIM) * D_DIM);
            double s0 = 0.0, s1 = 0.0, s2 = 0.0, s3 = 0.0;
            #pragma unroll 4
            for (int k = lane * 4; k < D_DIM; k += 256) {
                float4 w4 = *(const float4*)(wp + k);
                s0 += xs[k]     * (double)w4.x;
                s1 += xs[k + 1] * (double)w4.y;
                s2 += xs[k + 2] * (double)w4.z;
                s3 += xs[k + 3] * (double)w4.w;
            }
            double s = (s0 + s1) + (s2 + s3);
            #pragma unroll
            for (int off = 32; off > 0; off >>= 1) s += __shfl_xor(s, off);
            if (lane == 0) red[row] = s;
        }
        __syncthreads();

        if (wv == 0) {   // epilogue: lane = expert
            double zr = red[lane] + (double)br[lane];
            double zn = red[E_DIM + lane] + (double)bn[lane];
            double sp = fmax(zn, 0.0) + log1p(exp(-fabs(zn)));
            double nl = zr + (double)eps[(size_t)tok * E_DIM + lane] * sp;
            double v = nl, m0 = 0.0, denom = 0.0;
            bool selected = false;
            int rankedIdx = 0;
            #pragma unroll
            for (int k = 0; k < KTOP; ++k) {
                double mv = v; int mi = lane;
                #pragma unroll
                for (int off = 32; off > 0; off >>= 1) {
                    double ov = __shfl_xor(mv, off);
                    int    oi = __shfl_xor(mi, off);
                    if (ov > mv || (ov == mv && oi < mi)) { mv = ov; mi = oi; }
                }
                if (k == 0) m0 = mv;
                denom += exp(mv - m0);
                if (lane == mi) { selected = true; v = -INFINITY; }
                if (lane == k) rankedIdx = mi;
            }
            float p = selected ? (float)(exp(nl - m0) / denom) : 0.f;
            out_probs[(size_t)tok * E_DIM + lane] = p;
            if (lane < KTOP) out_idx[(size_t)tok * KTOP + lane] = (float)rankedIdx;
        }
        __syncthreads();   // xs reused next iteration
    }
}

extern "C" void kernel_launch(void* const* d_in, const int* in_sizes, int n_in,
                              void* d_out, int out_size, void* d_ws, size_t ws_size,
                              hipStream_t stream) {
    const float* mh  = (const float*)d_in[0];
    const float* Wr  = (const float*)d_in[1];
    const float* br  = (const float*)d_in[2];
    const float* Wn  = (const float*)d_in[3];
    const float* bn  = (const float*)d_in[4];
    const float* eps = (const float*)d_in[5];

    const int ntok = in_sizes[0] / D_DIM;                     // 16384
    float* out_probs = (float*)d_out;                         // [ntok][64]
    float* out_idx   = (float*)d_out + (size_t)ntok * E_DIM;  // [ntok][8] as float

    unsigned int* cnt = (unsigned int*)d_ws;
    int* list = (int*)((char*)d_ws + WS_LIST);
    unsigned short* img = (unsigned short*)((char*)d_ws + WS_IMG);

    hipLaunchKernelGGL(preconv, dim3(256), dim3(256), 0, stream, Wr, Wn, img, cnt);
    hipLaunchKernelGGL(router_main, dim3(ntok / BM), dim3(512), 32768, stream,
                       mh, img, br, bn, eps, out_probs, out_idx, cnt, list);
    hipLaunchKernelGGL(refine_fp64, dim3(1024), dim3(256), 0, stream,
                       mh, Wr, br, Wn, bn, eps, out_probs, out_idx, cnt, list);
}

// Round 13
// 254.319 us; speedup vs baseline: 2.5767x; 1.3397x over previous
//
#include <hip/hip_runtime.h>
#include <math.h>

#define D_DIM 4096
#define E_DIM 64
#define KTOP 8
#define TAU 2e-4f     // ambiguity threshold: ~33 sigma of split-bf16 GEMM error (~6e-6 RMS)
#define BM 32         // tokens per block; 512 thr -> grid 512 -> 2 blocks/CU = 16 waves/CU
#define BKT 32        // k per tile
#define NT (D_DIM / BKT)   // 128 tiles

// workspace layout (bytes)
#define WS_CNT 0
#define WS_LIST 1024
#define WS_IMG 66560  // 1024 + 64KB list; 16B aligned

typedef __attribute__((ext_vector_type(8))) short bf16x8;
typedef __attribute__((ext_vector_type(4))) float f32x4;

#define MFMA(a, b, c) __builtin_amdgcn_mfma_f32_16x16x32_bf16(a, b, c, 0, 0, 0)

// ---- split 8 fp32 -> hi/lo bf16x8 via v_cvt_pk_bf16_f32 (RNE) ----
__device__ inline void split8(float4 p, float4 q, bf16x8& h8, bf16x8& l8) {
    float xx[8] = {p.x, p.y, p.z, p.w, q.x, q.y, q.z, q.w};
    union { unsigned int w[4]; bf16x8 v; } H, L;
    #pragma unroll
    for (int i = 0; i < 4; ++i) {
        float a = xx[2 * i], b = xx[2 * i + 1];
        unsigned int hw;
        asm("v_cvt_pk_bf16_f32 %0, %1, %2" : "=v"(hw) : "v"(a), "v"(b));
        float ha = __uint_as_float(hw << 16);
        float hb = __uint_as_float(hw & 0xFFFF0000u);
        float ra = a - ha, rb = b - hb;           // exact residuals
        unsigned int lw;
        asm("v_cvt_pk_bf16_f32 %0, %1, %2" : "=v"(lw) : "v"(ra), "v"(rb));
        H.w[i] = hw; L.w[i] = lw;
    }
    h8 = H.v; l8 = L.v;
}

// ---- preconvert weights: Wr||Wn -> hi/lo bf16 image, fragment-linear per k-tile ----
// image (ushort idx): tile kt: hi at kt*8192 + koff*1024 + col*8 + j ; lo at +4096
__global__ __launch_bounds__(256)
void preconv(const float* __restrict__ Wr, const float* __restrict__ Wn,
             unsigned short* __restrict__ img, unsigned int* __restrict__ cnt)
{
    if (blockIdx.x == 0 && threadIdx.x == 0) *cnt = 0u;   // fused zero_cnt
    int t = blockIdx.x * 256 + threadIdx.x;      // 0..65535
    int kt = t >> 9, rem = t & 511;
    int koff = rem >> 7, col = rem & 127;
    int k = kt * 32 + koff * 8;
    const float* base = (col < E_DIM) ? (Wr + (size_t)col * D_DIM)
                                      : (Wn + (size_t)(col - E_DIM) * D_DIM);
    float4 x0 = *(const float4*)(base + k);
    float4 x1 = *(const float4*)(base + k + 4);
    bf16x8 h8, l8;
    split8(x0, x1, h8, l8);                       // RNE, same as router's A-split
    size_t o = (size_t)kt * 8192 + koff * 1024 + col * 8;
    *(bf16x8*)(img + o) = h8;
    *(bf16x8*)(img + o + 4096) = l8;
}

// ---- main: split-bf16 MFMA GEMM + epilogue + flagging ----
// 8 waves: wr = wv>>2 rowgroup (16 tokens), wc = wv&3 colgroup (32 cols).
// RULE #20 (r8/r10): all cross-iteration staging in NAMED scalars.
// SCHEDULE (r12 post-mortem): ALL global issues at TOP of section, right after
// the barrier — __syncthreads drains vmcnt(0), so loads issued just before a
// barrier (r12) expose full L2/L3 latency every tile; issued just after, they
// get a full compute section in flight and the drain is ~free.
__global__ __launch_bounds__(512, 2)
void router_main(const float* __restrict__ mh,
                 const unsigned short* __restrict__ Wimg,
                 const float* __restrict__ br, const float* __restrict__ bn,
                 const float* __restrict__ eps,
                 float* __restrict__ out_probs, float* __restrict__ out_idx,
                 unsigned int* __restrict__ cnt, int* __restrict__ list)
{
    extern __shared__ char smem[];
    unsigned short* Bb = (unsigned short*)smem;   // [2][8192] ushorts (32KB), GEMM phase
    float* zs = (float*)smem;                     // [32][132] overlay, epilogue (16.9KB)

    const int tid  = threadIdx.x;
    const int lane = tid & 63;
    const int wv   = tid >> 6;       // 0..7
    const int wr   = wv >> 2;        // rowgroup 0..1 (16 tokens each)
    const int wc   = wv & 3;         // colgroup 0..3 (32 cols each)
    const int tok0 = blockIdx.x * BM;
    const int rloc = lane & 15;
    const int koff = lane >> 4;      // 0..3

    const float* aptr = mh + (size_t)(tok0 + wr * 16 + rloc) * D_DIM + koff * 8;

    const int boff0 = koff * 1024 + (wc * 32 + rloc) * 8;        // col-frag 0
    const int boff1 = boff0 + 16 * 8;                            // col-frag 1

    const int4* gimg = (const int4*)Wimg;   // 1024 int4 per k-tile
    int4* Bb4 = (int4*)Bb;                  // 1024 int4 per buffer

    f32x4 acc0 = {0.f, 0.f, 0.f, 0.f};
    f32x4 acc1 = {0.f, 0.f, 0.f, 0.f};

    auto tile_mfma = [&](const unsigned short* bb, bf16x8 ah, bf16x8 al) {
        bf16x8 bh0 = *(const bf16x8*)(bb + boff0);
        bf16x8 bh1 = *(const bf16x8*)(bb + boff1);
        bf16x8 bl0 = *(const bf16x8*)(bb + 4096 + boff0);
        bf16x8 bl1 = *(const bf16x8*)(bb + 4096 + boff1);
        acc0 = MFMA(ah, bh0, acc0);
        acc0 = MFMA(al, bh0, acc0);
        acc0 = MFMA(ah, bl0, acc0);
        acc1 = MFMA(ah, bh1, acc1);
        acc1 = MFMA(al, bh1, acc1);
        acc1 = MFMA(ah, bl1, acc1);
    };

    // prologue: stage B tile0 -> Bb[0]; load A(0)
    Bb4[tid]       = gimg[tid];
    Bb4[512 + tid] = gimg[512 + tid];
    int4 p1a, p1b, p2a, p2b;
    float4 a0A = *(const float4*)(aptr + 0), a1A = *(const float4*)(aptr + 4);
    float4 a0B, a1B;

    for (int kt = 0; kt < NT; kt += 2) {
        // ---- EVEN tile kt: compute from Bb[0] ----
        __syncthreads();                          // Bb[0] (tile kt) visible; prior-section loads long in flight
        {   // issue B(kt+1) + A(kt+1) NOW (kt+1 <= 127 always)
            const int4* g1 = gimg + (size_t)(kt + 1) * 1024 + tid;
            p1a = g1[0]; p1b = g1[512];
            a0B = *(const float4*)(aptr + (kt + 1) * 32);
            a1B = *(const float4*)(aptr + (kt + 1) * 32 + 4);
        }
        {
            bf16x8 ah, al;
            split8(a0A, a1A, ah, al);
            tile_mfma(Bb, ah, al);
        }
        // write B(kt+1) -> Bb[1] (p1 loads have had ~a full compute section)
        Bb4[1024 + tid] = p1a;
        Bb4[1536 + tid] = p1b;

        // ---- ODD tile kt+1: compute from Bb[1] ----
        __syncthreads();                          // Bb[1] (tile kt+1) visible
        if (kt + 2 < NT) {  // issue B(kt+2) + A(kt+2)
            const int4* g2 = gimg + (size_t)(kt + 2) * 1024 + tid;
            p2a = g2[0]; p2b = g2[512];
            a0A = *(const float4*)(aptr + (kt + 2) * 32);
            a1A = *(const float4*)(aptr + (kt + 2) * 32 + 4);
        }
        {
            bf16x8 ah, al;
            split8(a0B, a1B, ah, al);
            tile_mfma(Bb + 8192, ah, al);
        }
        if (kt + 2 < NT) {                        // write B(kt+2) -> Bb[0]
            Bb4[tid]       = p2a;
            Bb4[512 + tid] = p2b;
        }
    }
    __syncthreads();   // all ds_reads done before zs overlays Bb

    // acc -> zs (+bias). C-layout: col=lane&15, row=(lane>>4)*4+reg (m89-verified)
    {
        const int c0 = wc * 32 + rloc;
        const int c1 = c0 + 16;
        const float bias0 = (c0 < E_DIM) ? br[c0] : bn[c0 - E_DIM];
        const float bias1 = (c1 < E_DIM) ? br[c1] : bn[c1 - E_DIM];
        #pragma unroll
        for (int rg = 0; rg < 4; ++rg) {
            const int row = wr * 16 + koff * 4 + rg;
            zs[row * 132 + c0] = acc0[rg] + bias0;
            zs[row * 132 + c1] = acc1[rg] + bias1;
        }
    }
    __syncthreads();

    // noisy logits, in-place into route half of zs (each quad owned by one thread)
    {
        const int t  = tid >> 4;                 // 0..31
        const int e0 = (tid & 15) << 2;          // 0..60
        float4 ep = *(const float4*)(eps + (size_t)(tok0 + t) * E_DIM + e0);
        float epv[4] = {ep.x, ep.y, ep.z, ep.w};
        #pragma unroll
        for (int j = 0; j < 4; ++j) {
            float zr = zs[t * 132 + e0 + j];
            float zn = zs[t * 132 + 64 + e0 + j];
            float sp = fmaxf(zn, 0.f) + log1pf(expf(-fabsf(zn)));
            zs[t * 132 + e0 + j] = zr + epv[j] * sp;
        }
    }
    __syncthreads();

    // top-8 (+9th for gap) + masked softmax: wave wv handles tokens wv*4..wv*4+3
    for (int tk = 0; tk < 4; ++tk) {
        int t = wv * 4 + tk;
        float v0 = zs[t * 132 + lane];
        float v  = v0;
        float m0 = 0.f, denom = 0.f, prev = 0.f, mingap = INFINITY;
        bool selected = false;
        int rankedIdx = 0;
        #pragma unroll
        for (int k = 0; k < KTOP + 1; ++k) {
            float mv = v; int mi = lane;
            #pragma unroll
            for (int off = 32; off > 0; off >>= 1) {
                float ov = __shfl_xor(mv, off);
                int   oi = __shfl_xor(mi, off);
                if (ov > mv || (ov == mv && oi < mi)) { mv = ov; mi = oi; }
            }
            if (k == 0) m0 = mv; else mingap = fminf(mingap, prev - mv);
            prev = mv;
            if (k < KTOP) {
                denom += expf(mv - m0);
                if (lane == mi) { selected = true; v = -INFINITY; }
                if (lane == k) rankedIdx = mi;
            }
        }
        float p = selected ? expf(v0 - m0) / denom : 0.f;
        size_t tg = (size_t)(tok0 + t);
        out_probs[tg * E_DIM + lane] = p;
        if (lane < KTOP) out_idx[tg * KTOP + lane] = (float)rankedIdx;
        if (mingap < TAU && lane == 0) {
            unsigned int wpos = atomicAdd(cnt, 1u);
            list[wpos] = (int)tg;
        }
    }
}

// ---- fp64 exact recompute for flagged tokens: 1 block/token ----
// No LDS x-staging: old version read xs[lane*4+i*256] doubles = 16-way LDS
// bank conflict (banks {0,8,16,24}) on every inner read. x row (16KB) is
// L1-resident across the 128 W-rows instead; loads fully coalesced.
__global__ __launch_bounds__(256)
void refine_fp64(const float* __restrict__ mh,
                 const float* __restrict__ Wr, const float* __restrict__ br,
                 const float* __restrict__ Wn, const float* __restrict__ bn,
                 const float* __restrict__ eps,
                 float* __restrict__ out_probs, float* __restrict__ out_idx,
                 const unsigned int* __restrict__ cnt, const int* __restrict__ list)
{
    __shared__ double red[128];
    const unsigned int n = *cnt;
    const int tid  = threadIdx.x;
    const int lane = tid & 63;
    const int wv   = tid >> 6;     // 0..3

    for (unsigned int i = blockIdx.x; i < n; i += gridDim.x) {
        const int tok = list[i];
        const float* xb = mh + (size_t)tok * D_DIM;

        for (int r = 0; r < 32; ++r) {
            const int row = wv * 32 + r;
            const float* wp = (row < E_DIM) ? (Wr + (size_t)row * D_DIM)
                                            : (Wn + (size_t)(row - E_DIM) * D_DIM);
            double s0 = 0.0, s1 = 0.0, s2 = 0.0, s3 = 0.0;
            #pragma unroll 4
            for (int k = lane * 4; k < D_DIM; k += 256) {
                float4 xv = *(const float4*)(xb + k);
                float4 w4 = *(const float4*)(wp + k);
                s0 += (double)xv.x * (double)w4.x;
                s1 += (double)xv.y * (double)w4.y;
                s2 += (double)xv.z * (double)w4.z;
                s3 += (double)xv.w * (double)w4.w;
            }
            double s = (s0 + s1) + (s2 + s3);
            #pragma unroll
            for (int off = 32; off > 0; off >>= 1) s += __shfl_xor(s, off);
            if (lane == 0) red[row] = s;
        }
        __syncthreads();

        if (wv == 0) {   // epilogue: lane = expert
            double zr = red[lane] + (double)br[lane];
            double zn = red[E_DIM + lane] + (double)bn[lane];
            double sp = fmax(zn, 0.0) + log1p(exp(-fabs(zn)));
            double nl = zr + (double)eps[(size_t)tok * E_DIM + lane] * sp;
            double v = nl, m0 = 0.0, denom = 0.0;
            bool selected = false;
            int rankedIdx = 0;
            #pragma unroll
            for (int k = 0; k < KTOP; ++k) {
                double mv = v; int mi = lane;
                #pragma unroll
                for (int off = 32; off > 0; off >>= 1) {
                    double ov = __shfl_xor(mv, off);
                    int    oi = __shfl_xor(mi, off);
                    if (ov > mv || (ov == mv && oi < mi)) { mv = ov; mi = oi; }
                }
                if (k == 0) m0 = mv;
                denom += exp(mv - m0);
                if (lane == mi) { selected = true; v = -INFINITY; }
                if (lane == k) rankedIdx = mi;
            }
            float p = selected ? (float)(exp(nl - m0) / denom) : 0.f;
            out_probs[(size_t)tok * E_DIM + lane] = p;
            if (lane < KTOP) out_idx[(size_t)tok * KTOP + lane] = (float)rankedIdx;
        }
        __syncthreads();   // red reused next iteration
    }
}

extern "C" void kernel_launch(void* const* d_in, const int* in_sizes, int n_in,
                              void* d_out, int out_size, void* d_ws, size_t ws_size,
                              hipStream_t stream) {
    const float* mh  = (const float*)d_in[0];
    const float* Wr  = (const float*)d_in[1];
    const float* br  = (const float*)d_in[2];
    const float* Wn  = (const float*)d_in[3];
    const float* bn  = (const float*)d_in[4];
    const float* eps = (const float*)d_in[5];

    const int ntok = in_sizes[0] / D_DIM;                     // 16384
    float* out_probs = (float*)d_out;                         // [ntok][64]
    float* out_idx   = (float*)d_out + (size_t)ntok * E_DIM;  // [ntok][8] as float

    unsigned int* cnt = (unsigned int*)d_ws;
    int* list = (int*)((char*)d_ws + WS_LIST);
    unsigned short* img = (unsigned short*)((char*)d_ws + WS_IMG);

    hipLaunchKernelGGL(preconv, dim3(256), dim3(256), 0, stream, Wr, Wn, img, cnt);
    hipLaunchKernelGGL(router_main, dim3(ntok / BM), dim3(512), 32768, stream,
                       mh, img, br, bn, eps, out_probs, out_idx, cnt, list);
    hipLaunchKernelGGL(refine_fp64, dim3(1024), dim3(256), 0, stream,
                       mh, Wr, br, Wn, bn, eps, out_probs, out_idx, cnt, list);
}

// Round 14
// 246.750 us; speedup vs baseline: 2.6557x; 1.0307x over previous
//
#include <hip/hip_runtime.h>
#include <math.h>

#define D_DIM 4096
#define E_DIM 64
#define KTOP 8
#define TAU 2e-4f     // ambiguity threshold: ~33 sigma of split-bf16 GEMM error (~6e-6 RMS)
#define BM 32         // tokens per block; 512 thr, grid 512
#define NT 128        // k-tiles of 32

// workspace layout (bytes)
#define WS_LIST 1024
#define WS_IMG 66560  // 1024 + 64KB list; 16B aligned

typedef __attribute__((ext_vector_type(8))) short bf16x8;
typedef __attribute__((ext_vector_type(4))) float f32x4;

#define MFMA(a, b, c) __builtin_amdgcn_mfma_f32_16x16x32_bf16(a, b, c, 0, 0, 0)

typedef const __attribute__((address_space(1))) void gas_void;
typedef __attribute__((address_space(3))) void las_void;
// async global->LDS, 16B per lane; LDS dest is wave-uniform base + lane*16,
// our tid-linear layout satisfies this exactly (guide m97/m104).
#define GLL16(src, dst) \
    __builtin_amdgcn_global_load_lds((gas_void*)(src), (las_void*)(dst), 16, 0, 0)

// ---- split 8 fp32 -> hi/lo bf16x8 via v_cvt_pk_bf16_f32 (RNE) ----
__device__ inline void split8(float4 p, float4 q, bf16x8& h8, bf16x8& l8) {
    float xx[8] = {p.x, p.y, p.z, p.w, q.x, q.y, q.z, q.w};
    union { unsigned int w[4]; bf16x8 v; } H, L;
    #pragma unroll
    for (int i = 0; i < 4; ++i) {
        float a = xx[2 * i], b = xx[2 * i + 1];
        unsigned int hw;
        asm("v_cvt_pk_bf16_f32 %0, %1, %2" : "=v"(hw) : "v"(a), "v"(b));
        float ha = __uint_as_float(hw << 16);
        float hb = __uint_as_float(hw & 0xFFFF0000u);
        float ra = a - ha, rb = b - hb;           // exact residuals
        unsigned int lw;
        asm("v_cvt_pk_bf16_f32 %0, %1, %2" : "=v"(lw) : "v"(ra), "v"(rb));
        H.w[i] = hw; L.w[i] = lw;
    }
    h8 = H.v; l8 = L.v;
}

// ---- preconvert weights: Wr||Wn -> hi/lo bf16 image, fragment-linear per k-tile ----
// image (ushort idx): tile kt: hi at kt*8192 + koff*1024 + col*8 + j ; lo at +4096
__global__ __launch_bounds__(256)
void preconv(const float* __restrict__ Wr, const float* __restrict__ Wn,
             unsigned short* __restrict__ img, unsigned int* __restrict__ cnt)
{
    if (blockIdx.x == 0 && threadIdx.x == 0) *cnt = 0u;   // fused zero_cnt
    int t = blockIdx.x * 256 + threadIdx.x;      // 0..65535
    int kt = t >> 9, rem = t & 511;
    int koff = rem >> 7, col = rem & 127;
    int k = kt * 32 + koff * 8;
    const float* base = (col < E_DIM) ? (Wr + (size_t)col * D_DIM)
                                      : (Wn + (size_t)(col - E_DIM) * D_DIM);
    float4 x0 = *(const float4*)(base + k);
    float4 x1 = *(const float4*)(base + k + 4);
    bf16x8 h8, l8;
    split8(x0, x1, h8, l8);                       // RNE, same as router's A-split
    size_t o = (size_t)kt * 8192 + koff * 1024 + col * 8;
    *(bf16x8*)(img + o) = h8;
    *(bf16x8*)(img + o + 4096) = l8;
}

// ---- main: split-bf16 MFMA GEMM + epilogue + flagging ----
// 8 waves: wr = wv>>2 rowgroup (16 tokens), wc = wv&3 colgroup (32 cols).
// Pipeline (r13 post-mortem: VGPR=36 proved compiler sank all reg prefetches):
//   B via global_load_lds (no SSA result -> cannot sink, no reg round-trip)
//   A via 2-deep named-slot reg prefetch (rule #20), pinned by sched_barrier(0)
//   raw s_barrier + counted "vmcnt(2) lgkmcnt(0)" so A stays in flight across
//   the barrier (__syncthreads would drain vmcnt(0)).
// vmcnt ledger (steady state, end of section kt):
//   outstanding = [A(kt+1)x2, gllB(kt+1)x2, A(kt+2)x2] -> vmcnt(2) retires
//   B + A(kt+1) (used right after next barrier anyway), keeps A(kt+2) flying.
__global__ __launch_bounds__(512, 2)
void router_main(const float* __restrict__ mh,
                 const unsigned short* __restrict__ Wimg,
                 const float* __restrict__ br, const float* __restrict__ bn,
                 const float* __restrict__ eps,
                 float* __restrict__ out_probs, float* __restrict__ out_idx,
                 unsigned int* __restrict__ cnt, int* __restrict__ list)
{
    __shared__ int4 Bb4s[2048];          // [2][1024] int4 = 32KB, B double-buffer
    __shared__ float zs[BM * 132];       // 16.9KB epilogue buffer (separate: gll races overlays)

    const int tid  = threadIdx.x;
    const int lane = tid & 63;
    const int wv   = tid >> 6;       // 0..7
    const int wr   = wv >> 2;        // rowgroup 0..1 (16 tokens each)
    const int wc   = wv & 3;         // colgroup 0..3 (32 cols each)
    const int tok0 = blockIdx.x * BM;
    const int rloc = lane & 15;
    const int koff = lane >> 4;      // 0..3

    const float* aptr = mh + (size_t)(tok0 + wr * 16 + rloc) * D_DIM + koff * 8;

    const unsigned short* Bb = (const unsigned short*)Bb4s;
    const int boff0 = koff * 1024 + (wc * 32 + rloc) * 8;        // col-frag 0
    const int boff1 = boff0 + 16 * 8;                            // col-frag 1

    const int4* gimg = (const int4*)Wimg;   // 1024 int4 per k-tile

    f32x4 acc0 = {0.f, 0.f, 0.f, 0.f};
    f32x4 acc1 = {0.f, 0.f, 0.f, 0.f};

    // A prefetch slots: 4 tiles deep rotation (2-deep prefetch), named (rule #20)
    float4 a00, a01, a10, a11, a20, a21, a30, a31;

    // ---- prologue: gll B(0) -> Bb[0]; load A(0),A(1) ----
    GLL16(gimg + tid,       Bb4s + tid);
    GLL16(gimg + 512 + tid, Bb4s + 512 + tid);
    __builtin_amdgcn_sched_barrier(0);
    a00 = *(const float4*)(aptr + 0);  a01 = *(const float4*)(aptr + 4);
    a10 = *(const float4*)(aptr + 32); a11 = *(const float4*)(aptr + 36);
    __builtin_amdgcn_sched_barrier(0);
    // outstanding: [gll x2, A x4] -> vmcnt(4): B(0) landed, A still in flight
    asm volatile("s_waitcnt vmcnt(4)" ::: "memory");
    __builtin_amdgcn_s_barrier();

    auto section = [&](int kt, float4& aC0, float4& aC1,
                       float4& aN0, float4& aN1, int buf) {
        // 1) issue B(kt+1) glls FIRST (ordering matters for the vmcnt count)
        if (kt + 1 < NT) {
            const int4* g = gimg + (size_t)(kt + 1) * 1024 + tid;
            int4* d = Bb4s + (buf ^ 1) * 1024 + tid;
            GLL16(g, d);
            GLL16(g + 512, d + 512);
        }
        __builtin_amdgcn_sched_barrier(0);
        // 2) issue A(kt+2) into the slot 2 ahead
        if (kt + 2 < NT) {
            aN0 = *(const float4*)(aptr + (kt + 2) * 32);
            aN1 = *(const float4*)(aptr + (kt + 2) * 32 + 4);
        }
        __builtin_amdgcn_sched_barrier(0);
        // 3) compute tile kt from Bb[buf] (A(kt) load retired by prior vmcnt)
        {
            bf16x8 ah, al;
            split8(aC0, aC1, ah, al);
            const unsigned short* bb = Bb + buf * 8192;
            bf16x8 bh0 = *(const bf16x8*)(bb + boff0);
            bf16x8 bh1 = *(const bf16x8*)(bb + boff1);
            bf16x8 bl0 = *(const bf16x8*)(bb + 4096 + boff0);
            bf16x8 bl1 = *(const bf16x8*)(bb + 4096 + boff1);
            acc0 = MFMA(ah, bh0, acc0);
            acc0 = MFMA(al, bh0, acc0);
            acc0 = MFMA(ah, bl0, acc0);
            acc1 = MFMA(ah, bh1, acc1);
            acc1 = MFMA(al, bh1, acc1);
            acc1 = MFMA(ah, bl1, acc1);
        }
        // 4) counted wait: B(kt+1) landed + own ds_reads retired; A(kt+2) stays
        //    in flight across the barrier. lgkmcnt(0) makes next section's gll
        //    overwrite of Bb[buf] safe (all reads retired before barrier).
        if (kt + 2 < NT) {
            asm volatile("s_waitcnt vmcnt(2) lgkmcnt(0)" ::: "memory");
        } else {
            asm volatile("s_waitcnt vmcnt(0) lgkmcnt(0)" ::: "memory");
        }
        __builtin_amdgcn_s_barrier();
    };

    for (int kt = 0; kt < NT; kt += 4) {
        section(kt + 0, a00, a01, a20, a21, 0);
        section(kt + 1, a10, a11, a30, a31, 1);
        section(kt + 2, a20, a21, a00, a01, 0);
        section(kt + 3, a30, a31, a10, a11, 1);
    }
    __syncthreads();

    // acc -> zs (+bias). C-layout: col=lane&15, row=(lane>>4)*4+reg (m89-verified)
    {
        const int c0 = wc * 32 + rloc;
        const int c1 = c0 + 16;
        const float bias0 = (c0 < E_DIM) ? br[c0] : bn[c0 - E_DIM];
        const float bias1 = (c1 < E_DIM) ? br[c1] : bn[c1 - E_DIM];
        #pragma unroll
        for (int rg = 0; rg < 4; ++rg) {
            const int row = wr * 16 + koff * 4 + rg;
            zs[row * 132 + c0] = acc0[rg] + bias0;
            zs[row * 132 + c1] = acc1[rg] + bias1;
        }
    }
    __syncthreads();

    // noisy logits, in-place into route half of zs (each quad owned by one thread)
    {
        const int t  = tid >> 4;                 // 0..31
        const int e0 = (tid & 15) << 2;          // 0..60
        float4 ep = *(const float4*)(eps + (size_t)(tok0 + t) * E_DIM + e0);
        float epv[4] = {ep.x, ep.y, ep.z, ep.w};
        #pragma unroll
        for (int j = 0; j < 4; ++j) {
            float zr = zs[t * 132 + e0 + j];
            float zn = zs[t * 132 + 64 + e0 + j];
            float sp = fmaxf(zn, 0.f) + log1pf(expf(-fabsf(zn)));
            zs[t * 132 + e0 + j] = zr + epv[j] * sp;
        }
    }
    __syncthreads();

    // top-8 (+9th for gap) + masked softmax: wave wv handles tokens wv*4..wv*4+3
    for (int tk = 0; tk < 4; ++tk) {
        int t = wv * 4 + tk;
        float v0 = zs[t * 132 + lane];
        float v  = v0;
        float m0 = 0.f, denom = 0.f, prev = 0.f, mingap = INFINITY;
        bool selected = false;
        int rankedIdx = 0;
        #pragma unroll
        for (int k = 0; k < KTOP + 1; ++k) {
            float mv = v; int mi = lane;
            #pragma unroll
            for (int off = 32; off > 0; off >>= 1) {
                float ov = __shfl_xor(mv, off);
                int   oi = __shfl_xor(mi, off);
                if (ov > mv || (ov == mv && oi < mi)) { mv = ov; mi = oi; }
            }
            if (k == 0) m0 = mv; else mingap = fminf(mingap, prev - mv);
            prev = mv;
            if (k < KTOP) {
                denom += expf(mv - m0);
                if (lane == mi) { selected = true; v = -INFINITY; }
                if (lane == k) rankedIdx = mi;
            }
        }
        float p = selected ? expf(v0 - m0) / denom : 0.f;
        size_t tg = (size_t)(tok0 + t);
        out_probs[tg * E_DIM + lane] = p;
        if (lane < KTOP) out_idx[tg * KTOP + lane] = (float)rankedIdx;
        if (mingap < TAU && lane == 0) {
            unsigned int wpos = atomicAdd(cnt, 1u);
            list[wpos] = (int)tg;
        }
    }
}

// ---- fp64 exact recompute for flagged tokens: 1 block/token ----
// x row read direct from global (L1-resident across the 128 W-rows).
__global__ __launch_bounds__(256)
void refine_fp64(const float* __restrict__ mh,
                 const float* __restrict__ Wr, const float* __restrict__ br,
                 const float* __restrict__ Wn, const float* __restrict__ bn,
                 const float* __restrict__ eps,
                 float* __restrict__ out_probs, float* __restrict__ out_idx,
                 const unsigned int* __restrict__ cnt, const int* __restrict__ list)
{
    __shared__ double red[128];
    const unsigned int n = *cnt;
    const int tid  = threadIdx.x;
    const int lane = tid & 63;
    const int wv   = tid >> 6;     // 0..3

    for (unsigned int i = blockIdx.x; i < n; i += gridDim.x) {
        const int tok = list[i];
        const float* xb = mh + (size_t)tok * D_DIM;

        for (int r = 0; r < 32; ++r) {
            const int row = wv * 32 + r;
            const float* wp = (row < E_DIM) ? (Wr + (size_t)row * D_DIM)
                                            : (Wn + (size_t)(row - E_DIM) * D_DIM);
            double s0 = 0.0, s1 = 0.0, s2 = 0.0, s3 = 0.0;
            #pragma unroll 4
            for (int k = lane * 4; k < D_DIM; k += 256) {
                float4 xv = *(const float4*)(xb + k);
                float4 w4 = *(const float4*)(wp + k);
                s0 += (double)xv.x * (double)w4.x;
                s1 += (double)xv.y * (double)w4.y;
                s2 += (double)xv.z * (double)w4.z;
                s3 += (double)xv.w * (double)w4.w;
            }
            double s = (s0 + s1) + (s2 + s3);
            #pragma unroll
            for (int off = 32; off > 0; off >>= 1) s += __shfl_xor(s, off);
            if (lane == 0) red[row] = s;
        }
        __syncthreads();

        if (wv == 0) {   // epilogue: lane = expert
            double zr = red[lane] + (double)br[lane];
            double zn = red[E_DIM + lane] + (double)bn[lane];
            double sp = fmax(zn, 0.0) + log1p(exp(-fabs(zn)));
            double nl = zr + (double)eps[(size_t)tok * E_DIM + lane] * sp;
            double v = nl, m0 = 0.0, denom = 0.0;
            bool selected = false;
            int rankedIdx = 0;
            #pragma unroll
            for (int k = 0; k < KTOP; ++k) {
                double mv = v; int mi = lane;
                #pragma unroll
                for (int off = 32; off > 0; off >>= 1) {
                    double ov = __shfl_xor(mv, off);
                    int    oi = __shfl_xor(mi, off);
                    if (ov > mv || (ov == mv && oi < mi)) { mv = ov; mi = oi; }
                }
                if (k == 0) m0 = mv;
                denom += exp(mv - m0);
                if (lane == mi) { selected = true; v = -INFINITY; }
                if (lane == k) rankedIdx = mi;
            }
            float p = selected ? (float)(exp(nl - m0) / denom) : 0.f;
            out_probs[(size_t)tok * E_DIM + lane] = p;
            if (lane < KTOP) out_idx[(size_t)tok * KTOP + lane] = (float)rankedIdx;
        }
        __syncthreads();   // red reused next iteration
    }
}

extern "C" void kernel_launch(void* const* d_in, const int* in_sizes, int n_in,
                              void* d_out, int out_size, void* d_ws, size_t ws_size,
                              hipStream_t stream) {
    const float* mh  = (const float*)d_in[0];
    const float* Wr  = (const float*)d_in[1];
    const float* br  = (const float*)d_in[2];
    const float* Wn  = (const float*)d_in[3];
    const float* bn  = (const float*)d_in[4];
    const float* eps = (const float*)d_in[5];

    const int ntok = in_sizes[0] / D_DIM;                     // 16384
    float* out_probs = (float*)d_out;                         // [ntok][64]
    float* out_idx   = (float*)d_out + (size_t)ntok * E_DIM;  // [ntok][8] as float

    unsigned int* cnt = (unsigned int*)d_ws;
    int* list = (int*)((char*)d_ws + WS_LIST);
    unsigned short* img = (unsigned short*)((char*)d_ws + WS_IMG);

    hipLaunchKernelGGL(preconv, dim3(256), dim3(256), 0, stream, Wr, Wn, img, cnt);
    hipLaunchKernelGGL(router_main, dim3(ntok / BM), dim3(512), 0, stream,
                       mh, img, br, bn, eps, out_probs, out_idx, cnt, list);
    hipLaunchKernelGGL(refine_fp64, dim3(1024), dim3(256), 0, stream,
                       mh, Wr, br, Wn, bn, eps, out_probs, out_idx, cnt, list);
}

// Round 15
// 246.027 us; speedup vs baseline: 2.6635x; 1.0029x over previous
//
#include <hip/hip_runtime.h>
#include <math.h>

#define D_DIM 4096
#define E_DIM 64
#define KTOP 8
#define TAU 2e-4f     // ambiguity threshold: ~33 sigma of split-bf16 GEMM error (~6e-6 RMS)
#define BM 32         // tokens per block; 512 thr, grid 512
#define NT 128        // k-tiles of 32

// workspace layout (bytes)
#define WS_LIST 1024
#define WS_IMG 66560  // 1024 + 64KB list; 16B aligned

typedef __attribute__((ext_vector_type(8))) short bf16x8;
typedef __attribute__((ext_vector_type(4))) float f32x4;

#define MFMA(a, b, c) __builtin_amdgcn_mfma_f32_16x16x32_bf16(a, b, c, 0, 0, 0)

typedef const __attribute__((address_space(1))) void gas_void;
typedef __attribute__((address_space(3))) void las_void;
// async global->LDS, 16B per lane; LDS dest is wave-uniform base + lane*16,
// our tid-linear layout satisfies this exactly (guide m97/m104).
#define GLL16(src, dst) \
    __builtin_amdgcn_global_load_lds((gas_void*)(src), (las_void*)(dst), 16, 0, 0)

// ---- split 8 fp32 -> hi/lo bf16x8 via v_cvt_pk_bf16_f32 (RNE) ----
__device__ inline void split8(float4 p, float4 q, bf16x8& h8, bf16x8& l8) {
    float xx[8] = {p.x, p.y, p.z, p.w, q.x, q.y, q.z, q.w};
    union { unsigned int w[4]; bf16x8 v; } H, L;
    #pragma unroll
    for (int i = 0; i < 4; ++i) {
        float a = xx[2 * i], b = xx[2 * i + 1];
        unsigned int hw;
        asm("v_cvt_pk_bf16_f32 %0, %1, %2" : "=v"(hw) : "v"(a), "v"(b));
        float ha = __uint_as_float(hw << 16);
        float hb = __uint_as_float(hw & 0xFFFF0000u);
        float ra = a - ha, rb = b - hb;           // exact residuals
        unsigned int lw;
        asm("v_cvt_pk_bf16_f32 %0, %1, %2" : "=v"(lw) : "v"(ra), "v"(rb));
        H.w[i] = hw; L.w[i] = lw;
    }
    h8 = H.v; l8 = L.v;
}

// ---- preconvert weights: Wr||Wn -> hi/lo bf16 image, fragment-linear per k-tile ----
// image (ushort idx): tile kt: hi at kt*8192 + koff*1024 + col*8 + j ; lo at +4096
__global__ __launch_bounds__(256)
void preconv(const float* __restrict__ Wr, const float* __restrict__ Wn,
             unsigned short* __restrict__ img, unsigned int* __restrict__ cnt)
{
    if (blockIdx.x == 0 && threadIdx.x == 0) *cnt = 0u;   // fused zero_cnt
    int t = blockIdx.x * 256 + threadIdx.x;      // 0..65535
    int kt = t >> 9, rem = t & 511;
    int koff = rem >> 7, col = rem & 127;
    int k = kt * 32 + koff * 8;
    const float* base = (col < E_DIM) ? (Wr + (size_t)col * D_DIM)
                                      : (Wn + (size_t)(col - E_DIM) * D_DIM);
    float4 x0 = *(const float4*)(base + k);
    float4 x1 = *(const float4*)(base + k + 4);
    bf16x8 h8, l8;
    split8(x0, x1, h8, l8);                       // RNE, same as router's A-split
    size_t o = (size_t)kt * 8192 + koff * 1024 + col * 8;
    *(bf16x8*)(img + o) = h8;
    *(bf16x8*)(img + o + 4096) = l8;
}

// ---- main: split-bf16 MFMA GEMM + epilogue + flagging ----
// 8 waves: wr = wv>>2 rowgroup (16 tokens), wc = wv&3 colgroup (32 cols).
// Pipeline (r13 post-mortem: VGPR=36 proved compiler sank all reg prefetches):
//   B via global_load_lds (no SSA result -> cannot sink, no reg round-trip)
//   A via 2-deep named-slot reg prefetch (rule #20), pinned by sched_barrier(0)
//   raw s_barrier + counted "vmcnt(2) lgkmcnt(0)" so A stays in flight across
//   the barrier (__syncthreads would drain vmcnt(0)).
// vmcnt ledger (steady state, end of section kt):
//   outstanding = [A(kt+1)x2, gllB(kt+1)x2, A(kt+2)x2] -> vmcnt(2) retires
//   B + A(kt+1) (used right after next barrier anyway), keeps A(kt+2) flying.
__global__ __launch_bounds__(512, 2)
void router_main(const float* __restrict__ mh,
                 const unsigned short* __restrict__ Wimg,
                 const float* __restrict__ br, const float* __restrict__ bn,
                 const float* __restrict__ eps,
                 float* __restrict__ out_probs, float* __restrict__ out_idx,
                 unsigned int* __restrict__ cnt, int* __restrict__ list)
{
    __shared__ int4 Bb4s[2048];          // [2][1024] int4 = 32KB, B double-buffer
    __shared__ float zs[BM * 132];       // 16.9KB epilogue buffer (separate: gll races overlays)

    const int tid  = threadIdx.x;
    const int lane = tid & 63;
    const int wv   = tid >> 6;       // 0..7
    const int wr   = wv >> 2;        // rowgroup 0..1 (16 tokens each)
    const int wc   = wv & 3;         // colgroup 0..3 (32 cols each)
    const int tok0 = blockIdx.x * BM;
    const int rloc = lane & 15;
    const int koff = lane >> 4;      // 0..3

    const float* aptr = mh + (size_t)(tok0 + wr * 16 + rloc) * D_DIM + koff * 8;

    const unsigned short* Bb = (const unsigned short*)Bb4s;
    const int boff0 = koff * 1024 + (wc * 32 + rloc) * 8;        // col-frag 0
    const int boff1 = boff0 + 16 * 8;                            // col-frag 1

    const int4* gimg = (const int4*)Wimg;   // 1024 int4 per k-tile

    f32x4 acc0 = {0.f, 0.f, 0.f, 0.f};
    f32x4 acc1 = {0.f, 0.f, 0.f, 0.f};

    // A prefetch slots: 4 tiles deep rotation (2-deep prefetch), named (rule #20)
    float4 a00, a01, a10, a11, a20, a21, a30, a31;

    // ---- prologue: gll B(0) -> Bb[0]; load A(0),A(1) ----
    GLL16(gimg + tid,       Bb4s + tid);
    GLL16(gimg + 512 + tid, Bb4s + 512 + tid);
    __builtin_amdgcn_sched_barrier(0);
    a00 = *(const float4*)(aptr + 0);  a01 = *(const float4*)(aptr + 4);
    a10 = *(const float4*)(aptr + 32); a11 = *(const float4*)(aptr + 36);
    __builtin_amdgcn_sched_barrier(0);
    // outstanding: [gll x2, A x4] -> vmcnt(4): B(0) landed, A still in flight
    asm volatile("s_waitcnt vmcnt(4)" ::: "memory");
    __builtin_amdgcn_s_barrier();

    auto section = [&](int kt, float4& aC0, float4& aC1,
                       float4& aN0, float4& aN1, int buf) {
        // 1) issue B(kt+1) glls FIRST (ordering matters for the vmcnt count)
        if (kt + 1 < NT) {
            const int4* g = gimg + (size_t)(kt + 1) * 1024 + tid;
            int4* d = Bb4s + (buf ^ 1) * 1024 + tid;
            GLL16(g, d);
            GLL16(g + 512, d + 512);
        }
        __builtin_amdgcn_sched_barrier(0);
        // 2) issue A(kt+2) into the slot 2 ahead
        if (kt + 2 < NT) {
            aN0 = *(const float4*)(aptr + (kt + 2) * 32);
            aN1 = *(const float4*)(aptr + (kt + 2) * 32 + 4);
        }
        __builtin_amdgcn_sched_barrier(0);
        // 3) compute tile kt from Bb[buf] (A(kt) load retired by prior vmcnt)
        {
            bf16x8 ah, al;
            split8(aC0, aC1, ah, al);
            const unsigned short* bb = Bb + buf * 8192;
            bf16x8 bh0 = *(const bf16x8*)(bb + boff0);
            bf16x8 bh1 = *(const bf16x8*)(bb + boff1);
            bf16x8 bl0 = *(const bf16x8*)(bb + 4096 + boff0);
            bf16x8 bl1 = *(const bf16x8*)(bb + 4096 + boff1);
            acc0 = MFMA(ah, bh0, acc0);
            acc0 = MFMA(al, bh0, acc0);
            acc0 = MFMA(ah, bl0, acc0);
            acc1 = MFMA(ah, bh1, acc1);
            acc1 = MFMA(al, bh1, acc1);
            acc1 = MFMA(ah, bl1, acc1);
        }
        // 4) counted wait: B(kt+1) landed + own ds_reads retired; A(kt+2) stays
        //    in flight across the barrier. lgkmcnt(0) makes next section's gll
        //    overwrite of Bb[buf] safe (all reads retired before barrier).
        if (kt + 2 < NT) {
            asm volatile("s_waitcnt vmcnt(2) lgkmcnt(0)" ::: "memory");
        } else {
            asm volatile("s_waitcnt vmcnt(0) lgkmcnt(0)" ::: "memory");
        }
        __builtin_amdgcn_s_barrier();
    };

    for (int kt = 0; kt < NT; kt += 4) {
        section(kt + 0, a00, a01, a20, a21, 0);
        section(kt + 1, a10, a11, a30, a31, 1);
        section(kt + 2, a20, a21, a00, a01, 0);
        section(kt + 3, a30, a31, a10, a11, 1);
    }
    __syncthreads();

    // acc -> zs (+bias). C-layout: col=lane&15, row=(lane>>4)*4+reg (m89-verified)
    {
        const int c0 = wc * 32 + rloc;
        const int c1 = c0 + 16;
        const float bias0 = (c0 < E_DIM) ? br[c0] : bn[c0 - E_DIM];
        const float bias1 = (c1 < E_DIM) ? br[c1] : bn[c1 - E_DIM];
        #pragma unroll
        for (int rg = 0; rg < 4; ++rg) {
            const int row = wr * 16 + koff * 4 + rg;
            zs[row * 132 + c0] = acc0[rg] + bias0;
            zs[row * 132 + c1] = acc1[rg] + bias1;
        }
    }
    __syncthreads();

    // noisy logits, in-place into route half of zs (each quad owned by one thread)
    {
        const int t  = tid >> 4;                 // 0..31
        const int e0 = (tid & 15) << 2;          // 0..60
        float4 ep = *(const float4*)(eps + (size_t)(tok0 + t) * E_DIM + e0);
        float epv[4] = {ep.x, ep.y, ep.z, ep.w};
        #pragma unroll
        for (int j = 0; j < 4; ++j) {
            float zr = zs[t * 132 + e0 + j];
            float zn = zs[t * 132 + 64 + e0 + j];
            float sp = fmaxf(zn, 0.f) + log1pf(expf(-fabsf(zn)));
            zs[t * 132 + e0 + j] = zr + epv[j] * sp;
        }
    }
    __syncthreads();

    // top-8 (+9th for gap) + masked softmax: wave wv handles tokens wv*4..wv*4+3
    for (int tk = 0; tk < 4; ++tk) {
        int t = wv * 4 + tk;
        float v0 = zs[t * 132 + lane];
        float v  = v0;
        float m0 = 0.f, denom = 0.f, prev = 0.f, mingap = INFINITY;
        bool selected = false;
        int rankedIdx = 0;
        #pragma unroll
        for (int k = 0; k < KTOP + 1; ++k) {
            float mv = v; int mi = lane;
            #pragma unroll
            for (int off = 32; off > 0; off >>= 1) {
                float ov = __shfl_xor(mv, off);
                int   oi = __shfl_xor(mi, off);
                if (ov > mv || (ov == mv && oi < mi)) { mv = ov; mi = oi; }
            }
            if (k == 0) m0 = mv; else mingap = fminf(mingap, prev - mv);
            prev = mv;
            if (k < KTOP) {
                denom += expf(mv - m0);
                if (lane == mi) { selected = true; v = -INFINITY; }
                if (lane == k) rankedIdx = mi;
            }
        }
        float p = selected ? expf(v0 - m0) / denom : 0.f;
        size_t tg = (size_t)(tok0 + t);
        out_probs[tg * E_DIM + lane] = p;
        if (lane < KTOP) out_idx[tg * KTOP + lane] = (float)rankedIdx;
        if (mingap < TAU && lane == 0) {
            unsigned int wpos = atomicAdd(cnt, 1u);
            list[wpos] = (int)tg;
        }
    }
}

// ---- fp64 exact recompute for flagged tokens: 1 block/token ----
// x row read direct from global (L1-resident across the 128 W-rows).
__global__ __launch_bounds__(256)
void refine_fp64(const float* __restrict__ mh,
                 const float* __restrict__ Wr, const float* __restrict__ br,
                 const float* __restrict__ Wn, const float* __restrict__ bn,
                 const float* __restrict__ eps,
                 float* __restrict__ out_probs, float* __restrict__ out_idx,
                 const unsigned int* __restrict__ cnt, const int* __restrict__ list)
{
    __shared__ double red[128];
    const unsigned int n = *cnt;
    const int tid  = threadIdx.x;
    const int lane = tid & 63;
    const int wv   = tid >> 6;     // 0..3

    for (unsigned int i = blockIdx.x; i < n; i += gridDim.x) {
        const int tok = list[i];
        const float* xb = mh + (size_t)tok * D_DIM;

        for (int r = 0; r < 32; ++r) {
            const int row = wv * 32 + r;
            const float* wp = (row < E_DIM) ? (Wr + (size_t)row * D_DIM)
                                            : (Wn + (size_t)(row - E_DIM) * D_DIM);
            double s0 = 0.0, s1 = 0.0, s2 = 0.0, s3 = 0.0;
            #pragma unroll 4
            for (int k = lane * 4; k < D_DIM; k += 256) {
                float4 xv = *(const float4*)(xb + k);
                float4 w4 = *(const float4*)(wp + k);
                s0 += (double)xv.x * (double)w4.x;
                s1 += (double)xv.y * (double)w4.y;
                s2 += (double)xv.z * (double)w4.z;
                s3 += (double)xv.w * (double)w4.w;
            }
            double s = (s0 + s1) + (s2 + s3);
            #pragma unroll
            for (int off = 32; off > 0; off >>= 1) s += __shfl_xor(s, off);
            if (lane == 0) red[row] = s;
        }
        __syncthreads();

        if (wv == 0) {   // epilogue: lane = expert
            double zr = red[lane] + (double)br[lane];
            double zn = red[E_DIM + lane] + (double)bn[lane];
            double sp = fmax(zn, 0.0) + log1p(exp(-fabs(zn)));
            double nl = zr + (double)eps[(size_t)tok * E_DIM + lane] * sp;
            double v = nl, m0 = 0.0, denom = 0.0;
            bool selected = false;
            int rankedIdx = 0;
            #pragma unroll
            for (int k = 0; k < KTOP; ++k) {
                double mv = v; int mi = lane;
                #pragma unroll
                for (int off = 32; off > 0; off >>= 1) {
                    double ov = __shfl_xor(mv, off);
                    int    oi = __shfl_xor(mi, off);
                    if (ov > mv || (ov == mv && oi < mi)) { mv = ov; mi = oi; }
                }
                if (k == 0) m0 = mv;
                denom += exp(mv - m0);
                if (lane == mi) { selected = true; v = -INFINITY; }
                if (lane == k) rankedIdx = mi;
            }
            float p = selected ? (float)(exp(nl - m0) / denom) : 0.f;
            out_probs[(size_t)tok * E_DIM + lane] = p;
            if (lane < KTOP) out_idx[(size_t)tok * KTOP + lane] = (float)rankedIdx;
        }
        __syncthreads();   // red reused next iteration
    }
}

extern "C" void kernel_launch(void* const* d_in, const int* in_sizes, int n_in,
                              void* d_out, int out_size, void* d_ws, size_t ws_size,
                              hipStream_t stream) {
    const float* mh  = (const float*)d_in[0];
    const float* Wr  = (const float*)d_in[1];
    const float* br  = (const float*)d_in[2];
    const float* Wn  = (const float*)d_in[3];
    const float* bn  = (const float*)d_in[4];
    const float* eps = (const float*)d_in[5];

    const int ntok = in_sizes[0] / D_DIM;                     // 16384
    float* out_probs = (float*)d_out;                         // [ntok][64]
    float* out_idx   = (float*)d_out + (size_t)ntok * E_DIM;  // [ntok][8] as float

    unsigned int* cnt = (unsigned int*)d_ws;
    int* list = (int*)((char*)d_ws + WS_LIST);
    unsigned short* img = (unsigned short*)((char*)d_ws + WS_IMG);

    hipLaunchKernelGGL(preconv, dim3(256), dim3(256), 0, stream, Wr, Wn, img, cnt);
    hipLaunchKernelGGL(router_main, dim3(ntok / BM), dim3(512), 0, stream,
                       mh, img, br, bn, eps, out_probs, out_idx, cnt, list);
    hipLaunchKernelGGL(refine_fp64, dim3(1024), dim3(256), 0, stream,
                       mh, Wr, br, Wn, bn, eps, out_probs, out_idx, cnt, list);
}

// Round 17
// 232.568 us; speedup vs baseline: 2.8176x; 1.0579x over previous
//
#include <hip/hip_runtime.h>
#include <math.h>

#define D_DIM 4096
#define E_DIM 64
#define KTOP 8
#define TAU 2e-4f     // ambiguity threshold: ~33 sigma of split-bf16 GEMM error (~6e-6 RMS)
#define BM 64         // tokens per block; 512 thr, grid 256 = 1 block/CU, single round
#define NTS 64        // k-sections of 64 (each = two 32-k image tiles)
#define STB 49152     // bytes per pipeline stage: B 32KB + A 16KB
#define NST 3         // pipeline stages (consume kt, kt+1 landed, kt+2 in flight)

// workspace layout (bytes)
#define WS_LIST 1024
#define WS_IMG 66560  // 1024 + 64KB list; 16B aligned

typedef __attribute__((ext_vector_type(8))) short bf16x8;
typedef __attribute__((ext_vector_type(4))) float f32x4;

#define MFMA(a, b, c) __builtin_amdgcn_mfma_f32_16x16x32_bf16(a, b, c, 0, 0, 0)

typedef const __attribute__((address_space(1))) void gas_void;
typedef __attribute__((address_space(3))) void las_void;
#define GLL16(src, dst) \
    __builtin_amdgcn_global_load_lds((gas_void*)(src), (las_void*)(dst), 16, 0, 0)
#define SCHED_FENCE() __builtin_amdgcn_sched_barrier(0)

// ---- split 8 fp32 -> hi/lo bf16x8 via v_cvt_pk_bf16_f32 (RNE) ----
__device__ inline void split8(float4 p, float4 q, bf16x8& h8, bf16x8& l8) {
    float xx[8] = {p.x, p.y, p.z, p.w, q.x, q.y, q.z, q.w};
    union { unsigned int w[4]; bf16x8 v; } H, L;
    #pragma unroll
    for (int i = 0; i < 4; ++i) {
        float a = xx[2 * i], b = xx[2 * i + 1];
        unsigned int hw;
        asm("v_cvt_pk_bf16_f32 %0, %1, %2" : "=v"(hw) : "v"(a), "v"(b));
        float ha = __uint_as_float(hw << 16);
        float hb = __uint_as_float(hw & 0xFFFF0000u);
        float ra = a - ha, rb = b - hb;           // exact residuals
        unsigned int lw;
        asm("v_cvt_pk_bf16_f32 %0, %1, %2" : "=v"(lw) : "v"(ra), "v"(rb));
        H.w[i] = hw; L.w[i] = lw;
    }
    h8 = H.v; l8 = L.v;
}

// ---- preconvert weights: Wr||Wn -> hi/lo bf16 image, fragment-linear per 32-k tile ----
// image (ushort idx): tile kt: hi at kt*8192 + koff*1024 + col*8 + j ; lo at +4096
__global__ __launch_bounds__(256)
void preconv(const float* __restrict__ Wr, const float* __restrict__ Wn,
             unsigned short* __restrict__ img, unsigned int* __restrict__ cnt)
{
    if (blockIdx.x == 0 && threadIdx.x == 0) *cnt = 0u;   // fused zero_cnt
    int t = blockIdx.x * 256 + threadIdx.x;      // 0..65535
    int kt = t >> 9, rem = t & 511;
    int koff = rem >> 7, col = rem & 127;
    int k = kt * 32 + koff * 8;
    const float* base = (col < E_DIM) ? (Wr + (size_t)col * D_DIM)
                                      : (Wn + (size_t)(col - E_DIM) * D_DIM);
    float4 x0 = *(const float4*)(base + k);
    float4 x1 = *(const float4*)(base + k + 4);
    bf16x8 h8, l8;
    split8(x0, x1, h8, l8);
    size_t o = (size_t)kt * 8192 + koff * 1024 + col * 8;
    *(bf16x8*)(img + o) = h8;
    *(bf16x8*)(img + o + 4096) = l8;
}

// ---- main: split-bf16 MFMA GEMM, ALL staging via global_load_lds ----
// 8 waves: wr = wv>>1 rowgroup (16 tokens), wc = wv&1 colgroup (64 cols).
// r15/r16 post-mortem: any C++ register prefetch gets sunk (VGPR=36..40) and
// inline-asm loads crashed. global_load_lds is the only sink-proof primitive
// verified on this HW -> A is staged through LDS too, remapped per-lane to
// [kquad][row] 16B granules (gll source is per-lane; dest is linear).
// 3-stage pipeline, counted vmcnt: issue stage kt+2 (6 glls), compute kt%3,
// wait vmcnt(6) (= stage kt+1 landed, kt+2 still flying ~1.7 sections).
__global__ __launch_bounds__(512)
void router_main(const float* __restrict__ mh,
                 const unsigned short* __restrict__ Wimg,
                 const float* __restrict__ br, const float* __restrict__ bn,
                 const float* __restrict__ eps,
                 float* __restrict__ out_probs, float* __restrict__ out_idx,
                 unsigned int* __restrict__ cnt, int* __restrict__ list)
{
    extern __shared__ char smem[];       // NST*STB = 144KB dynamic
    float* zs = (float*)smem;            // [64][132] epilogue overlay (post-drain)

    const int tid  = threadIdx.x;
    const int lane = tid & 63;
    const int wv   = tid >> 6;       // 0..7
    const int wr   = wv >> 1;        // rowgroup 0..3 (16 tokens each)
    const int wc   = wv & 1;         // colgroup 0..1 (64 cols each)
    const int tok0 = blockIdx.x * BM;
    const int rloc = lane & 15;
    const int koff = lane >> 4;      // 0..3
    const int row  = wr * 16 + rloc; // 0..63

    int boff[4];
    #pragma unroll
    for (int fc = 0; fc < 4; ++fc)
        boff[fc] = koff * 1024 + (wc * 64 + fc * 16 + rloc) * 8;   // ushort idx

    const int4* gimg = (const int4*)Wimg;   // 1024 int4 per 32-k tile
    // A gll source granule g = c*512+tid: row=g&63, kquad=g>>6 (4 fp32 = 16B)
    const float* arow = mh + (size_t)(tok0 + (tid & 63)) * D_DIM;
    const int aq0 = (tid >> 6) * 4;          // call 0: kquads 0..7
    const int aq1 = aq0 + 32;                // call 1: kquads 8..15

    f32x4 acc[4];
    #pragma unroll
    for (int fc = 0; fc < 4; ++fc) acc[fc] = {0.f, 0.f, 0.f, 0.f};

    auto stage_issue = [&](int t) {
        char* sb = smem + (t % NST) * STB;
        const int4* gB = gimg + (size_t)t * 2048 + tid;   // 2 image tiles
        int4* dB = (int4*)sb + tid;
        GLL16(gB, dB);
        GLL16(gB + 512,  dB + 512);
        GLL16(gB + 1024, dB + 1024);
        GLL16(gB + 1536, dB + 1536);
        int4* dA = (int4*)(sb + 32768) + tid;
        GLL16(arow + t * 64 + aq0, dA);
        GLL16(arow + t * 64 + aq1, dA + 512);
    };

    // ---- prologue: stage 0 and 1 in flight; wait stage 0 ----
    stage_issue(0);
    SCHED_FENCE();
    stage_issue(1);
    SCHED_FENCE();
    asm volatile("s_waitcnt vmcnt(6)" ::: "memory");
    SCHED_FENCE();
    __builtin_amdgcn_s_barrier();
    SCHED_FENCE();

    for (int kt = 0; kt < NTS; ++kt) {
        if (kt + 2 < NTS) stage_issue(kt + 2);
        SCHED_FENCE();
        // compute stage kt%NST: two 32-k subtiles
        {
            const char* sb = smem + (kt % NST) * STB;
            const unsigned short* Bst = (const unsigned short*)sb;
            const char* sa = sb + 32768;
            #pragma unroll
            for (int s = 0; s < 2; ++s) {
                const int kf = s * 8 + 2 * koff;
                float4 f0 = *(const float4*)(sa + (kf * 64 + row) * 16);
                float4 f1 = *(const float4*)(sa + ((kf + 1) * 64 + row) * 16);
                bf16x8 ah, al;
                split8(f0, f1, ah, al);
                const unsigned short* bb = Bst + s * 8192;
                #pragma unroll
                for (int fc = 0; fc < 4; ++fc) {
                    bf16x8 bh = *(const bf16x8*)(bb + boff[fc]);
                    bf16x8 bl = *(const bf16x8*)(bb + 4096 + boff[fc]);
                    acc[fc] = MFMA(ah, bh, acc[fc]);
                    acc[fc] = MFMA(al, bh, acc[fc]);
                    acc[fc] = MFMA(ah, bl, acc[fc]);
                }
            }
        }
        SCHED_FENCE();
        // counted wait: stage kt+1 landed; stage kt+2 (6 newest) keeps flying
        if (kt + 2 < NTS) {
            asm volatile("s_waitcnt vmcnt(6) lgkmcnt(0)" ::: "memory");
        } else {
            asm volatile("s_waitcnt vmcnt(0) lgkmcnt(0)" ::: "memory");
        }
        SCHED_FENCE();
        __builtin_amdgcn_s_barrier();
        SCHED_FENCE();
    }
    // loop exit: fully drained + barrier -> zs overlay safe

    // acc -> zs (+bias). C-layout: col=lane&15, row=(lane>>4)*4+reg (m89-verified)
    #pragma unroll
    for (int fc = 0; fc < 4; ++fc) {
        const int col = wc * 64 + fc * 16 + rloc;
        const float bias = (col < E_DIM) ? br[col] : bn[col - E_DIM];
        #pragma unroll
        for (int rg = 0; rg < 4; ++rg) {
            const int r = wr * 16 + koff * 4 + rg;
            zs[r * 132 + col] = acc[fc][rg] + bias;
        }
    }
    __syncthreads();

    // noisy logits, in-place into route half of zs (each octet owned by one thread)
    {
        const int t  = tid >> 3;                 // 0..63
        const int e0 = (tid & 7) << 3;
        const float* ep = eps + (size_t)(tok0 + t) * E_DIM + e0;
        #pragma unroll
        for (int j = 0; j < 8; ++j) {
            float zr = zs[t * 132 + e0 + j];
            float zn = zs[t * 132 + 64 + e0 + j];
            float sp = fmaxf(zn, 0.f) + log1pf(expf(-fabsf(zn)));
            zs[t * 132 + e0 + j] = zr + ep[j] * sp;
        }
    }
    __syncthreads();

    // top-8 (+9th for gap) + masked softmax: wave wv handles tokens wv*8..wv*8+7
    for (int tk = 0; tk < 8; ++tk) {
        int t = wv * 8 + tk;
        float v0 = zs[t * 132 + lane];
        float v  = v0;
        float m0 = 0.f, denom = 0.f, prev = 0.f, mingap = INFINITY;
        bool selected = false;
        int rankedIdx = 0;
        #pragma unroll
        for (int k = 0; k < KTOP + 1; ++k) {
            float mv = v; int mi = lane;
            #pragma unroll
            for (int off = 32; off > 0; off >>= 1) {
                float ov = __shfl_xor(mv, off);
                int   oi = __shfl_xor(mi, off);
                if (ov > mv || (ov == mv && oi < mi)) { mv = ov; mi = oi; }
            }
            if (k == 0) m0 = mv; else mingap = fminf(mingap, prev - mv);
            prev = mv;
            if (k < KTOP) {
                denom += expf(mv - m0);
                if (lane == mi) { selected = true; v = -INFINITY; }
                if (lane == k) rankedIdx = mi;
            }
        }
        float p = selected ? expf(v0 - m0) / denom : 0.f;
        size_t tg = (size_t)(tok0 + t);
        out_probs[tg * E_DIM + lane] = p;
        if (lane < KTOP) out_idx[tg * KTOP + lane] = (float)rankedIdx;
        if (mingap < TAU && lane == 0) {
            unsigned int wpos = atomicAdd(cnt, 1u);
            list[wpos] = (int)tg;
        }
    }
}

// ---- fp64 exact recompute for flagged tokens: 1 block/token ----
__global__ __launch_bounds__(256)
void refine_fp64(const float* __restrict__ mh,
                 const float* __restrict__ Wr, const float* __restrict__ br,
                 const float* __restrict__ Wn, const float* __restrict__ bn,
                 const float* __restrict__ eps,
                 float* __restrict__ out_probs, float* __restrict__ out_idx,
                 const unsigned int* __restrict__ cnt, const int* __restrict__ list)
{
    __shared__ double red[128];
    const unsigned int n = *cnt;
    const int tid  = threadIdx.x;
    const int lane = tid & 63;
    const int wv   = tid >> 6;     // 0..3

    for (unsigned int i = blockIdx.x; i < n; i += gridDim.x) {
        const int tok = list[i];
        const float* xb = mh + (size_t)tok * D_DIM;

        for (int r = 0; r < 32; ++r) {
            const int rrow = wv * 32 + r;
            const float* wp = (rrow < E_DIM) ? (Wr + (size_t)rrow * D_DIM)
                                             : (Wn + (size_t)(rrow - E_DIM) * D_DIM);
            double s0 = 0.0, s1 = 0.0, s2 = 0.0, s3 = 0.0;
            #pragma unroll 4
            for (int k = lane * 4; k < D_DIM; k += 256) {
                float4 xv = *(const float4*)(xb + k);
                float4 w4 = *(const float4*)(wp + k);
                s0 += (double)xv.x * (double)w4.x;
                s1 += (double)xv.y * (double)w4.y;
                s2 += (double)xv.z * (double)w4.z;
                s3 += (double)xv.w * (double)w4.w;
            }
            double s = (s0 + s1) + (s2 + s3);
            #pragma unroll
            for (int off = 32; off > 0; off >>= 1) s += __shfl_xor(s, off);
            if (lane == 0) red[rrow] = s;
        }
        __syncthreads();

        if (wv == 0) {   // epilogue: lane = expert
            double zr = red[lane] + (double)br[lane];
            double zn = red[E_DIM + lane] + (double)bn[lane];
            double sp = fmax(zn, 0.0) + log1p(exp(-fabs(zn)));
            double nl = zr + (double)eps[(size_t)tok * E_DIM + lane] * sp;
            double v = nl, m0 = 0.0, denom = 0.0;
            bool selected = false;
            int rankedIdx = 0;
            #pragma unroll
            for (int k = 0; k < KTOP; ++k) {
                double mv = v; int mi = lane;
                #pragma unroll
                for (int off = 32; off > 0; off >>= 1) {
                    double ov = __shfl_xor(mv, off);
                    int    oi = __shfl_xor(mi, off);
                    if (ov > mv || (ov == mv && oi < mi)) { mv = ov; mi = oi; }
                }
                if (k == 0) m0 = mv;
                denom += exp(mv - m0);
                if (lane == mi) { selected = true; v = -INFINITY; }
                if (lane == k) rankedIdx = mi;
            }
            float p = selected ? (float)(exp(nl - m0) / denom) : 0.f;
            out_probs[(size_t)tok * E_DIM + lane] = p;
            if (lane < KTOP) out_idx[(size_t)tok * KTOP + lane] = (float)rankedIdx;
        }
        __syncthreads();   // red reused next iteration
    }
}

extern "C" void kernel_launch(void* const* d_in, const int* in_sizes, int n_in,
                              void* d_out, int out_size, void* d_ws, size_t ws_size,
                              hipStream_t stream) {
    const float* mh  = (const float*)d_in[0];
    const float* Wr  = (const float*)d_in[1];
    const float* br  = (const float*)d_in[2];
    const float* Wn  = (const float*)d_in[3];
    const float* bn  = (const float*)d_in[4];
    const float* eps = (const float*)d_in[5];

    const int ntok = in_sizes[0] / D_DIM;                     // 16384
    float* out_probs = (float*)d_out;                         // [ntok][64]
    float* out_idx   = (float*)d_out + (size_t)ntok * E_DIM;  // [ntok][8] as float

    unsigned int* cnt = (unsigned int*)d_ws;
    int* list = (int*)((char*)d_ws + WS_LIST);
    unsigned short* img = (unsigned short*)((char*)d_ws + WS_IMG);

    hipLaunchKernelGGL(preconv, dim3(256), dim3(256), 0, stream, Wr, Wn, img, cnt);
    hipLaunchKernelGGL(router_main, dim3(ntok / BM), dim3(512), NST * STB, stream,
                       mh, img, br, bn, eps, out_probs, out_idx, cnt, list);
    hipLaunchKernelGGL(refine_fp64, dim3(1024), dim3(256), 0, stream,
                       mh, Wr, br, Wn, bn, eps, out_probs, out_idx, cnt, list);
}

// Round 18
// 232.250 us; speedup vs baseline: 2.8215x; 1.0014x over previous
//
#include <hip/hip_runtime.h>
#include <math.h>

#define D_DIM 4096
#define E_DIM 64
#define KTOP 8
#define TAU 2e-4f     // ambiguity threshold: ~33 sigma of split-bf16 GEMM error (~6e-6 RMS)
#define BM 64         // tokens per gemm block; 512 thr, grid 256
#define NTS 64        // k-sections of 64 (each = two 32-k image tiles)
#define STB 49152     // bytes per pipeline stage: B 32KB + A 16KB
#define NST 3         // pipeline stages

// workspace layout (bytes)
#define WS_LIST 1024
#define WS_IMG 66560              // 1024 + 64KB list; 16B aligned
#define WS_Z   (WS_IMG + 2097152) // after 2MB image: zbuf [16384][128] fp32 = 8MB

typedef __attribute__((ext_vector_type(8))) short bf16x8;
typedef __attribute__((ext_vector_type(4))) float f32x4;

#define MFMA(a, b, c) __builtin_amdgcn_mfma_f32_16x16x32_bf16(a, b, c, 0, 0, 0)

typedef const __attribute__((address_space(1))) void gas_void;
typedef __attribute__((address_space(3))) void las_void;
#define GLL16(src, dst) \
    __builtin_amdgcn_global_load_lds((gas_void*)(src), (las_void*)(dst), 16, 0, 0)
#define SCHED_FENCE() __builtin_amdgcn_sched_barrier(0)

// ---- split 8 fp32 -> hi/lo bf16x8 via v_cvt_pk_bf16_f32 (RNE) ----
__device__ inline void split8(float4 p, float4 q, bf16x8& h8, bf16x8& l8) {
    float xx[8] = {p.x, p.y, p.z, p.w, q.x, q.y, q.z, q.w};
    union { unsigned int w[4]; bf16x8 v; } H, L;
    #pragma unroll
    for (int i = 0; i < 4; ++i) {
        float a = xx[2 * i], b = xx[2 * i + 1];
        unsigned int hw;
        asm("v_cvt_pk_bf16_f32 %0, %1, %2" : "=v"(hw) : "v"(a), "v"(b));
        float ha = __uint_as_float(hw << 16);
        float hb = __uint_as_float(hw & 0xFFFF0000u);
        float ra = a - ha, rb = b - hb;           // exact residuals
        unsigned int lw;
        asm("v_cvt_pk_bf16_f32 %0, %1, %2" : "=v"(lw) : "v"(ra), "v"(rb));
        H.w[i] = hw; L.w[i] = lw;
    }
    h8 = H.v; l8 = L.v;
}

// ---- preconvert weights: Wr||Wn -> hi/lo bf16 image, fragment-linear per 32-k tile ----
__global__ __launch_bounds__(256)
void preconv(const float* __restrict__ Wr, const float* __restrict__ Wn,
             unsigned short* __restrict__ img, unsigned int* __restrict__ cnt)
{
    if (blockIdx.x == 0 && threadIdx.x == 0) *cnt = 0u;   // fused zero_cnt
    int t = blockIdx.x * 256 + threadIdx.x;      // 0..65535
    int kt = t >> 9, rem = t & 511;
    int koff = rem >> 7, col = rem & 127;
    int k = kt * 32 + koff * 8;
    const float* base = (col < E_DIM) ? (Wr + (size_t)col * D_DIM)
                                      : (Wn + (size_t)(col - E_DIM) * D_DIM);
    float4 x0 = *(const float4*)(base + k);
    float4 x1 = *(const float4*)(base + k + 4);
    bf16x8 h8, l8;
    split8(x0, x1, h8, l8);
    size_t o = (size_t)kt * 8192 + koff * 1024 + col * 8;
    *(bf16x8*)(img + o) = h8;
    *(bf16x8*)(img + o + 4096) = l8;
}

// ---- phase 1: split-bf16 MFMA GEMM only (r17 pipeline, verified) -> zbuf ----
__global__ __launch_bounds__(512)
void gemm_k(const float* __restrict__ mh,
            const unsigned short* __restrict__ Wimg,
            float* __restrict__ zbuf)
{
    extern __shared__ char smem[];       // NST*STB = 144KB dynamic

    const int tid  = threadIdx.x;
    const int lane = tid & 63;
    const int wv   = tid >> 6;       // 0..7
    const int wr   = wv >> 1;        // rowgroup 0..3 (16 tokens each)
    const int wc   = wv & 1;         // colgroup 0..1 (64 cols each)
    const int tok0 = blockIdx.x * BM;
    const int rloc = lane & 15;
    const int koff = lane >> 4;      // 0..3
    const int row  = wr * 16 + rloc; // 0..63

    int boff[4];
    #pragma unroll
    for (int fc = 0; fc < 4; ++fc)
        boff[fc] = koff * 1024 + (wc * 64 + fc * 16 + rloc) * 8;   // ushort idx

    const int4* gimg = (const int4*)Wimg;   // 1024 int4 per 32-k tile
    const float* arow = mh + (size_t)(tok0 + (tid & 63)) * D_DIM;
    const int aq0 = (tid >> 6) * 4;
    const int aq1 = aq0 + 32;

    f32x4 acc[4];
    #pragma unroll
    for (int fc = 0; fc < 4; ++fc) acc[fc] = {0.f, 0.f, 0.f, 0.f};

    auto stage_issue = [&](int t) {
        char* sb = smem + (t % NST) * STB;
        const int4* gB = gimg + (size_t)t * 2048 + tid;
        int4* dB = (int4*)sb + tid;
        GLL16(gB, dB);
        GLL16(gB + 512,  dB + 512);
        GLL16(gB + 1024, dB + 1024);
        GLL16(gB + 1536, dB + 1536);
        int4* dA = (int4*)(sb + 32768) + tid;
        GLL16(arow + t * 64 + aq0, dA);
        GLL16(arow + t * 64 + aq1, dA + 512);
    };

    stage_issue(0);
    SCHED_FENCE();
    stage_issue(1);
    SCHED_FENCE();
    asm volatile("s_waitcnt vmcnt(6)" ::: "memory");
    SCHED_FENCE();
    __builtin_amdgcn_s_barrier();
    SCHED_FENCE();

    for (int kt = 0; kt < NTS; ++kt) {
        if (kt + 2 < NTS) stage_issue(kt + 2);
        SCHED_FENCE();
        {
            const char* sb = smem + (kt % NST) * STB;
            const unsigned short* Bst = (const unsigned short*)sb;
            const char* sa = sb + 32768;
            #pragma unroll
            for (int s = 0; s < 2; ++s) {
                const int kf = s * 8 + 2 * koff;
                float4 f0 = *(const float4*)(sa + (kf * 64 + row) * 16);
                float4 f1 = *(const float4*)(sa + ((kf + 1) * 64 + row) * 16);
                bf16x8 ah, al;
                split8(f0, f1, ah, al);
                const unsigned short* bb = Bst + s * 8192;
                #pragma unroll
                for (int fc = 0; fc < 4; ++fc) {
                    bf16x8 bh = *(const bf16x8*)(bb + boff[fc]);
                    bf16x8 bl = *(const bf16x8*)(bb + 4096 + boff[fc]);
                    acc[fc] = MFMA(ah, bh, acc[fc]);
                    acc[fc] = MFMA(al, bh, acc[fc]);
                    acc[fc] = MFMA(ah, bl, acc[fc]);
                }
            }
        }
        SCHED_FENCE();
        if (kt + 2 < NTS) {
            asm volatile("s_waitcnt vmcnt(6) lgkmcnt(0)" ::: "memory");
        } else {
            asm volatile("s_waitcnt vmcnt(0) lgkmcnt(0)" ::: "memory");
        }
        SCHED_FENCE();
        __builtin_amdgcn_s_barrier();
        SCHED_FENCE();
    }

    // C-write: zbuf[tok][col], C-layout col=lane&15, row=(lane>>4)*4+reg (m89)
    float* zb = zbuf + (size_t)tok0 * 128;
    #pragma unroll
    for (int fc = 0; fc < 4; ++fc) {
        const int col = wc * 64 + fc * 16 + rloc;
        #pragma unroll
        for (int rg = 0; rg < 4; ++rg) {
            const int r = wr * 16 + koff * 4 + rg;
            zb[r * 128 + col] = acc[fc][rg];
        }
    }
}

// ---- phase 2: bias + noisy logits + top-9 + masked softmax + flagging ----
__global__ __launch_bounds__(256)
void epi_k(const float* __restrict__ zbuf,
           const float* __restrict__ br, const float* __restrict__ bn,
           const float* __restrict__ eps,
           float* __restrict__ out_probs, float* __restrict__ out_idx,
           unsigned int* __restrict__ cnt, int* __restrict__ list)
{
    __shared__ float zs[32 * 132];
    const int tid  = threadIdx.x;
    const int lane = tid & 63;
    const int wv   = tid >> 6;           // 0..3
    const int tok0 = blockIdx.x * 32;

    // load 32 tokens x 128 logits (1024 float4 quads)
    for (int i = tid; i < 1024; i += 256) {
        int t = i >> 5, q = i & 31;
        float4 v = *(const float4*)(zbuf + (size_t)(tok0 + t) * 128 + q * 4);
        int b = t * 132 + q * 4;
        zs[b] = v.x; zs[b + 1] = v.y; zs[b + 2] = v.z; zs[b + 3] = v.w;
    }
    __syncthreads();

    // bias + noisy logits, in-place into route half
    {
        const int t  = tid >> 3;             // 0..31
        const int e0 = (tid & 7) << 3;       // 0..56
        const float* ep = eps + (size_t)(tok0 + t) * E_DIM + e0;
        #pragma unroll
        for (int j = 0; j < 8; ++j) {
            float zr = zs[t * 132 + e0 + j] + br[e0 + j];
            float zn = zs[t * 132 + 64 + e0 + j] + bn[e0 + j];
            float sp = fmaxf(zn, 0.f) + log1pf(expf(-fabsf(zn)));
            zs[t * 132 + e0 + j] = zr + ep[j] * sp;
        }
    }
    __syncthreads();

    // top-8 (+9th for gap) + masked softmax: wave wv handles tokens wv*8..wv*8+7
    for (int tk = 0; tk < 8; ++tk) {
        int t = wv * 8 + tk;
        float v0 = zs[t * 132 + lane];
        float v  = v0;
        float m0 = 0.f, denom = 0.f, prev = 0.f, mingap = INFINITY;
        bool selected = false;
        int rankedIdx = 0;
        #pragma unroll
        for (int k = 0; k < KTOP + 1; ++k) {
            float mv = v; int mi = lane;
            #pragma unroll
            for (int off = 32; off > 0; off >>= 1) {
                float ov = __shfl_xor(mv, off);
                int   oi = __shfl_xor(mi, off);
                if (ov > mv || (ov == mv && oi < mi)) { mv = ov; mi = oi; }
            }
            if (k == 0) m0 = mv; else mingap = fminf(mingap, prev - mv);
            prev = mv;
            if (k < KTOP) {
                denom += expf(mv - m0);
                if (lane == mi) { selected = true; v = -INFINITY; }
                if (lane == k) rankedIdx = mi;
            }
        }
        float p = selected ? expf(v0 - m0) / denom : 0.f;
        size_t tg = (size_t)(tok0 + t);
        out_probs[tg * E_DIM + lane] = p;
        if (lane < KTOP) out_idx[tg * KTOP + lane] = (float)rankedIdx;
        if (mingap < TAU && lane == 0) {
            unsigned int wpos = atomicAdd(cnt, 1u);
            list[wpos] = (int)tg;
        }
    }
}

// ---- fp64 exact recompute for flagged tokens: 1 block/token ----
__global__ __launch_bounds__(256)
void refine_fp64(const float* __restrict__ mh,
                 const float* __restrict__ Wr, const float* __restrict__ br,
                 const float* __restrict__ Wn, const float* __restrict__ bn,
                 const float* __restrict__ eps,
                 float* __restrict__ out_probs, float* __restrict__ out_idx,
                 const unsigned int* __restrict__ cnt, const int* __restrict__ list)
{
    __shared__ double red[128];
    const unsigned int n = *cnt;
    const int tid  = threadIdx.x;
    const int lane = tid & 63;
    const int wv   = tid >> 6;     // 0..3

    for (unsigned int i = blockIdx.x; i < n; i += gridDim.x) {
        const int tok = list[i];
        const float* xb = mh + (size_t)tok * D_DIM;

        for (int r = 0; r < 32; ++r) {
            const int rrow = wv * 32 + r;
            const float* wp = (rrow < E_DIM) ? (Wr + (size_t)rrow * D_DIM)
                                             : (Wn + (size_t)(rrow - E_DIM) * D_DIM);
            double s0 = 0.0, s1 = 0.0, s2 = 0.0, s3 = 0.0;
            #pragma unroll 4
            for (int k = lane * 4; k < D_DIM; k += 256) {
                float4 xv = *(const float4*)(xb + k);
                float4 w4 = *(const float4*)(wp + k);
                s0 += (double)xv.x * (double)w4.x;
                s1 += (double)xv.y * (double)w4.y;
                s2 += (double)xv.z * (double)w4.z;
                s3 += (double)xv.w * (double)w4.w;
            }
            double s = (s0 + s1) + (s2 + s3);
            #pragma unroll
            for (int off = 32; off > 0; off >>= 1) s += __shfl_xor(s, off);
            if (lane == 0) red[rrow] = s;
        }
        __syncthreads();

        if (wv == 0) {   // epilogue: lane = expert
            double zr = red[lane] + (double)br[lane];
            double zn = red[E_DIM + lane] + (double)bn[lane];
            double sp = fmax(zn, 0.0) + log1p(exp(-fabs(zn)));
            double nl = zr + (double)eps[(size_t)tok * E_DIM + lane] * sp;
            double v = nl, m0 = 0.0, denom = 0.0;
            bool selected = false;
            int rankedIdx = 0;
            #pragma unroll
            for (int k = 0; k < KTOP; ++k) {
                double mv = v; int mi = lane;
                #pragma unroll
                for (int off = 32; off > 0; off >>= 1) {
                    double ov = __shfl_xor(mv, off);
                    int    oi = __shfl_xor(mi, off);
                    if (ov > mv || (ov == mv && oi < mi)) { mv = ov; mi = oi; }
                }
                if (k == 0) m0 = mv;
                denom += exp(mv - m0);
                if (lane == mi) { selected = true; v = -INFINITY; }
                if (lane == k) rankedIdx = mi;
            }
            float p = selected ? (float)(exp(nl - m0) / denom) : 0.f;
            out_probs[(size_t)tok * E_DIM + lane] = p;
            if (lane < KTOP) out_idx[(size_t)tok * KTOP + lane] = (float)rankedIdx;
        }
        __syncthreads();   // red reused next iteration
    }
}

extern "C" void kernel_launch(void* const* d_in, const int* in_sizes, int n_in,
                              void* d_out, int out_size, void* d_ws, size_t ws_size,
                              hipStream_t stream) {
    const float* mh  = (const float*)d_in[0];
    const float* Wr  = (const float*)d_in[1];
    const float* br  = (const float*)d_in[2];
    const float* Wn  = (const float*)d_in[3];
    const float* bn  = (const float*)d_in[4];
    const float* eps = (const float*)d_in[5];

    const int ntok = in_sizes[0] / D_DIM;                     // 16384
    float* out_probs = (float*)d_out;                         // [ntok][64]
    float* out_idx   = (float*)d_out + (size_t)ntok * E_DIM;  // [ntok][8] as float

    unsigned int* cnt = (unsigned int*)d_ws;
    int* list = (int*)((char*)d_ws + WS_LIST);
    unsigned short* img = (unsigned short*)((char*)d_ws + WS_IMG);
    float* zbuf = (float*)((char*)d_ws + WS_Z);

    hipLaunchKernelGGL(preconv, dim3(256), dim3(256), 0, stream, Wr, Wn, img, cnt);
    hipLaunchKernelGGL(gemm_k, dim3(ntok / BM), dim3(512), NST * STB, stream,
                       mh, img, zbuf);
    hipLaunchKernelGGL(epi_k, dim3(ntok / 32), dim3(256), 0, stream,
                       zbuf, br, bn, eps, out_probs, out_idx, cnt, list);
    hipLaunchKernelGGL(refine_fp64, dim3(1024), dim3(256), 0, stream,
                       mh, Wr, br, Wn, bn, eps, out_probs, out_idx, cnt, list);
}

// Round 19
// 215.565 us; speedup vs baseline: 3.0399x; 1.0774x over previous
//
#include <hip/hip_runtime.h>
#include <math.h>

#define D_DIM 4096
#define E_DIM 64
#define KTOP 8
#define TAU 2e-4f     // ambiguity threshold: ~33 sigma of split-bf16 GEMM error (~6e-6 RMS)
#define BM 64         // tokens per gemm block; 512 thr, grid 256
#define NTS 64        // k-sections of 64 (each = two 32-k image tiles)
#define STB 49152     // bytes per pipeline stage: B 32KB + A 16KB
#define NST 3         // pipeline stages

// workspace layout (bytes)
#define WS_LIST 1024
#define WS_IMG 66560              // 1024 + 64KB list; 16B aligned
#define WS_Z   (WS_IMG + 2097152) // after 2MB image: zbuf [16384][128] fp32 = 8MB

typedef __attribute__((ext_vector_type(8))) short bf16x8;
typedef __attribute__((ext_vector_type(4))) float f32x4;

#define MFMA(a, b, c) __builtin_amdgcn_mfma_f32_16x16x32_bf16(a, b, c, 0, 0, 0)

typedef const __attribute__((address_space(1))) void gas_void;
typedef __attribute__((address_space(3))) void las_void;
#define GLL16(src, dst) \
    __builtin_amdgcn_global_load_lds((gas_void*)(src), (las_void*)(dst), 16, 0, 0)
#define SCHED_FENCE() __builtin_amdgcn_sched_barrier(0)

// ---- split 8 fp32 -> hi/lo bf16x8 via v_cvt_pk_bf16_f32 (RNE) ----
__device__ inline void split8(float4 p, float4 q, bf16x8& h8, bf16x8& l8) {
    float xx[8] = {p.x, p.y, p.z, p.w, q.x, q.y, q.z, q.w};
    union { unsigned int w[4]; bf16x8 v; } H, L;
    #pragma unroll
    for (int i = 0; i < 4; ++i) {
        float a = xx[2 * i], b = xx[2 * i + 1];
        unsigned int hw;
        asm("v_cvt_pk_bf16_f32 %0, %1, %2" : "=v"(hw) : "v"(a), "v"(b));
        float ha = __uint_as_float(hw << 16);
        float hb = __uint_as_float(hw & 0xFFFF0000u);
        float ra = a - ha, rb = b - hb;           // exact residuals
        unsigned int lw;
        asm("v_cvt_pk_bf16_f32 %0, %1, %2" : "=v"(lw) : "v"(ra), "v"(rb));
        H.w[i] = hw; L.w[i] = lw;
    }
    h8 = H.v; l8 = L.v;
}

// ---- preconvert weights: Wr||Wn -> hi/lo bf16 image, fragment-linear per 32-k tile ----
__global__ __launch_bounds__(256)
void preconv(const float* __restrict__ Wr, const float* __restrict__ Wn,
             unsigned short* __restrict__ img, unsigned int* __restrict__ cnt)
{
    if (blockIdx.x == 0 && threadIdx.x == 0) *cnt = 0u;   // fused zero_cnt
    int t = blockIdx.x * 256 + threadIdx.x;      // 0..65535
    int kt = t >> 9, rem = t & 511;
    int koff = rem >> 7, col = rem & 127;
    int k = kt * 32 + koff * 8;
    const float* base = (col < E_DIM) ? (Wr + (size_t)col * D_DIM)
                                      : (Wn + (size_t)(col - E_DIM) * D_DIM);
    float4 x0 = *(const float4*)(base + k);
    float4 x1 = *(const float4*)(base + k + 4);
    bf16x8 h8, l8;
    split8(x0, x1, h8, l8);
    size_t o = (size_t)kt * 8192 + koff * 1024 + col * 8;
    *(bf16x8*)(img + o) = h8;
    *(bf16x8*)(img + o + 4096) = l8;
}

// ---- phase 1: split-bf16 MFMA GEMM -> zbuf ----
// r18 post-mortem: A gll source was lane=row (64 rows x 16KB stride per
// instruction = 64 scattered cache lines -> ~1024 line-requests/section,
// the 6000cyc/section stall). Fix: COALESCED A staging. Thread t stages LDS
// slot t (linear dest, gll-compatible) from source granule
// (token = t>>4, kq = (t&15) ^ (token&15)) -> each 16-lane group reads one
// token's contiguous 256B k-chunk (4 lines, internally permuted). Compute
// reads A at slot row*16 + (kf ^ (row&15)) -- same involution both sides
// (rule #21). Bank pattern within 16-lane phase: 2-way (free, m136).
__global__ __launch_bounds__(512)
void gemm_k(const float* __restrict__ mh,
            const unsigned short* __restrict__ Wimg,
            float* __restrict__ zbuf)
{
    extern __shared__ char smem[];       // NST*STB = 144KB dynamic

    const int tid  = threadIdx.x;
    const int lane = tid & 63;
    const int wv   = tid >> 6;       // 0..7
    const int wr   = wv >> 1;        // rowgroup 0..3 (16 tokens each)
    const int wc   = wv & 1;         // colgroup 0..1 (64 cols each)
    const int tok0 = blockIdx.x * BM;
    const int rloc = lane & 15;
    const int koff = lane >> 4;      // 0..3
    const int row  = wr * 16 + rloc; // 0..63
    const int rsw  = row & 15;       // read-side swizzle key

    int boff[4];
    #pragma unroll
    for (int fc = 0; fc < 4; ++fc)
        boff[fc] = koff * 1024 + (wc * 64 + fc * 16 + rloc) * 8;   // ushort idx

    const int4* gimg = (const int4*)Wimg;   // 1024 int4 per 32-k tile

    // A staging source (swizzled, coalesced): slot tid <- (a_tok, a_kq);
    // slot tid+512 <- (a_tok+32, same a_kq)  [(t+512)>>4 & 15 == t>>4 & 15]
    const int a_tok = tid >> 4;                       // 0..31
    const int a_kq  = (tid & 15) ^ (a_tok & 15);
    const float* asrc0 = mh + (size_t)(tok0 + a_tok) * D_DIM + a_kq * 4;
    const float* asrc1 = mh + (size_t)(tok0 + a_tok + 32) * D_DIM + a_kq * 4;

    f32x4 acc[4];
    #pragma unroll
    for (int fc = 0; fc < 4; ++fc) acc[fc] = {0.f, 0.f, 0.f, 0.f};

    auto stage_issue = [&](int t) {
        char* sb = smem + (t % NST) * STB;
        const int4* gB = gimg + (size_t)t * 2048 + tid;
        int4* dB = (int4*)sb + tid;
        GLL16(gB, dB);
        GLL16(gB + 512,  dB + 512);
        GLL16(gB + 1024, dB + 1024);
        GLL16(gB + 1536, dB + 1536);
        int4* dA = (int4*)(sb + 32768) + tid;
        GLL16(asrc0 + t * 64, dA);
        GLL16(asrc1 + t * 64, dA + 512);
    };

    stage_issue(0);
    SCHED_FENCE();
    stage_issue(1);
    SCHED_FENCE();
    asm volatile("s_waitcnt vmcnt(6)" ::: "memory");
    SCHED_FENCE();
    __builtin_amdgcn_s_barrier();
    SCHED_FENCE();

    for (int kt = 0; kt < NTS; ++kt) {
        if (kt + 2 < NTS) stage_issue(kt + 2);
        SCHED_FENCE();
        {
            const char* sb = smem + (kt % NST) * STB;
            const unsigned short* Bst = (const unsigned short*)sb;
            const char* sa = sb + 32768;   // A: 1024 granules [tok][kq^(tok&15)]
            #pragma unroll
            for (int s = 0; s < 2; ++s) {
                const int kf = s * 8 + 2 * koff;
                float4 f0 = *(const float4*)(sa + (row * 16 + ((kf)     ^ rsw)) * 16);
                float4 f1 = *(const float4*)(sa + (row * 16 + ((kf + 1) ^ rsw)) * 16);
                bf16x8 ah, al;
                split8(f0, f1, ah, al);
                const unsigned short* bb = Bst + s * 8192;
                #pragma unroll
                for (int fc = 0; fc < 4; ++fc) {
                    bf16x8 bh = *(const bf16x8*)(bb + boff[fc]);
                    bf16x8 bl = *(const bf16x8*)(bb + 4096 + boff[fc]);
                    acc[fc] = MFMA(ah, bh, acc[fc]);
                    acc[fc] = MFMA(al, bh, acc[fc]);
                    acc[fc] = MFMA(ah, bl, acc[fc]);
                }
            }
        }
        SCHED_FENCE();
        if (kt + 2 < NTS) {
            asm volatile("s_waitcnt vmcnt(6) lgkmcnt(0)" ::: "memory");
        } else {
            asm volatile("s_waitcnt vmcnt(0) lgkmcnt(0)" ::: "memory");
        }
        SCHED_FENCE();
        __builtin_amdgcn_s_barrier();
        SCHED_FENCE();
    }

    // C-write: zbuf[tok][col], C-layout col=lane&15, row=(lane>>4)*4+reg (m89)
    float* zb = zbuf + (size_t)tok0 * 128;
    #pragma unroll
    for (int fc = 0; fc < 4; ++fc) {
        const int col = wc * 64 + fc * 16 + rloc;
        #pragma unroll
        for (int rg = 0; rg < 4; ++rg) {
            const int r = wr * 16 + koff * 4 + rg;
            zb[r * 128 + col] = acc[fc][rg];
        }
    }
}

// ---- phase 2: bias + noisy logits + top-9 + masked softmax + flagging ----
__global__ __launch_bounds__(256)
void epi_k(const float* __restrict__ zbuf,
           const float* __restrict__ br, const float* __restrict__ bn,
           const float* __restrict__ eps,
           float* __restrict__ out_probs, float* __restrict__ out_idx,
           unsigned int* __restrict__ cnt, int* __restrict__ list)
{
    __shared__ float zs[32 * 132];
    const int tid  = threadIdx.x;
    const int lane = tid & 63;
    const int wv   = tid >> 6;           // 0..3
    const int tok0 = blockIdx.x * 32;

    for (int i = tid; i < 1024; i += 256) {
        int t = i >> 5, q = i & 31;
        float4 v = *(const float4*)(zbuf + (size_t)(tok0 + t) * 128 + q * 4);
        int b = t * 132 + q * 4;
        zs[b] = v.x; zs[b + 1] = v.y; zs[b + 2] = v.z; zs[b + 3] = v.w;
    }
    __syncthreads();

    {
        const int t  = tid >> 3;             // 0..31
        const int e0 = (tid & 7) << 3;       // 0..56
        const float* ep = eps + (size_t)(tok0 + t) * E_DIM + e0;
        #pragma unroll
        for (int j = 0; j < 8; ++j) {
            float zr = zs[t * 132 + e0 + j] + br[e0 + j];
            float zn = zs[t * 132 + 64 + e0 + j] + bn[e0 + j];
            float sp = fmaxf(zn, 0.f) + log1pf(expf(-fabsf(zn)));
            zs[t * 132 + e0 + j] = zr + ep[j] * sp;
        }
    }
    __syncthreads();

    for (int tk = 0; tk < 8; ++tk) {
        int t = wv * 8 + tk;
        float v0 = zs[t * 132 + lane];
        float v  = v0;
        float m0 = 0.f, denom = 0.f, prev = 0.f, mingap = INFINITY;
        bool selected = false;
        int rankedIdx = 0;
        #pragma unroll
        for (int k = 0; k < KTOP + 1; ++k) {
            float mv = v; int mi = lane;
            #pragma unroll
            for (int off = 32; off > 0; off >>= 1) {
                float ov = __shfl_xor(mv, off);
                int   oi = __shfl_xor(mi, off);
                if (ov > mv || (ov == mv && oi < mi)) { mv = ov; mi = oi; }
            }
            if (k == 0) m0 = mv; else mingap = fminf(mingap, prev - mv);
            prev = mv;
            if (k < KTOP) {
                denom += expf(mv - m0);
                if (lane == mi) { selected = true; v = -INFINITY; }
                if (lane == k) rankedIdx = mi;
            }
        }
        float p = selected ? expf(v0 - m0) / denom : 0.f;
        size_t tg = (size_t)(tok0 + t);
        out_probs[tg * E_DIM + lane] = p;
        if (lane < KTOP) out_idx[tg * KTOP + lane] = (float)rankedIdx;
        if (mingap < TAU && lane == 0) {
            unsigned int wpos = atomicAdd(cnt, 1u);
            list[wpos] = (int)tg;
        }
    }
}

// ---- fp64 exact recompute for flagged tokens: 1 block/token ----
__global__ __launch_bounds__(256)
void refine_fp64(const float* __restrict__ mh,
                 const float* __restrict__ Wr, const float* __restrict__ br,
                 const float* __restrict__ Wn, const float* __restrict__ bn,
                 const float* __restrict__ eps,
                 float* __restrict__ out_probs, float* __restrict__ out_idx,
                 const unsigned int* __restrict__ cnt, const int* __restrict__ list)
{
    __shared__ double red[128];
    const unsigned int n = *cnt;
    const int tid  = threadIdx.x;
    const int lane = tid & 63;
    const int wv   = tid >> 6;     // 0..3

    for (unsigned int i = blockIdx.x; i < n; i += gridDim.x) {
        const int tok = list[i];
        const float* xb = mh + (size_t)tok * D_DIM;

        for (int r = 0; r < 32; ++r) {
            const int rrow = wv * 32 + r;
            const float* wp = (rrow < E_DIM) ? (Wr + (size_t)rrow * D_DIM)
                                             : (Wn + (size_t)(rrow - E_DIM) * D_DIM);
            double s0 = 0.0, s1 = 0.0, s2 = 0.0, s3 = 0.0;
            #pragma unroll 4
            for (int k = lane * 4; k < D_DIM; k += 256) {
                float4 xv = *(const float4*)(xb + k);
                float4 w4 = *(const float4*)(wp + k);
                s0 += (double)xv.x * (double)w4.x;
                s1 += (double)xv.y * (double)w4.y;
                s2 += (double)xv.z * (double)w4.z;
                s3 += (double)xv.w * (double)w4.w;
            }
            double s = (s0 + s1) + (s2 + s3);
            #pragma unroll
            for (int off = 32; off > 0; off >>= 1) s += __shfl_xor(s, off);
            if (lane == 0) red[rrow] = s;
        }
        __syncthreads();

        if (wv == 0) {   // epilogue: lane = expert
            double zr = red[lane] + (double)br[lane];
            double zn = red[E_DIM + lane] + (double)bn[lane];
            double sp = fmax(zn, 0.0) + log1p(exp(-fabs(zn)));
            double nl = zr + (double)eps[(size_t)tok * E_DIM + lane] * sp;
            double v = nl, m0 = 0.0, denom = 0.0;
            bool selected = false;
            int rankedIdx = 0;
            #pragma unroll
            for (int k = 0; k < KTOP; ++k) {
                double mv = v; int mi = lane;
                #pragma unroll
                for (int off = 32; off > 0; off >>= 1) {
                    double ov = __shfl_xor(mv, off);
                    int    oi = __shfl_xor(mi, off);
                    if (ov > mv || (ov == mv && oi < mi)) { mv = ov; mi = oi; }
                }
                if (k == 0) m0 = mv;
                denom += exp(mv - m0);
                if (lane == mi) { selected = true; v = -INFINITY; }
                if (lane == k) rankedIdx = mi;
            }
            float p = selected ? (float)(exp(nl - m0) / denom) : 0.f;
            out_probs[(size_t)tok * E_DIM + lane] = p;
            if (lane < KTOP) out_idx[(size_t)tok * KTOP + lane] = (float)rankedIdx;
        }
        __syncthreads();   // red reused next iteration
    }
}

extern "C" void kernel_launch(void* const* d_in, const int* in_sizes, int n_in,
                              void* d_out, int out_size, void* d_ws, size_t ws_size,
                              hipStream_t stream) {
    const float* mh  = (const float*)d_in[0];
    const float* Wr  = (const float*)d_in[1];
    const float* br  = (const float*)d_in[2];
    const float* Wn  = (const float*)d_in[3];
    const float* bn  = (const float*)d_in[4];
    const float* eps = (const float*)d_in[5];

    const int ntok = in_sizes[0] / D_DIM;                     // 16384
    float* out_probs = (float*)d_out;                         // [ntok][64]
    float* out_idx   = (float*)d_out + (size_t)ntok * E_DIM;  // [ntok][8] as float

    unsigned int* cnt = (unsigned int*)d_ws;
    int* list = (int*)((char*)d_ws + WS_LIST);
    unsigned short* img = (unsigned short*)((char*)d_ws + WS_IMG);
    float* zbuf = (float*)((char*)d_ws + WS_Z);

    hipLaunchKernelGGL(preconv, dim3(256), dim3(256), 0, stream, Wr, Wn, img, cnt);
    hipLaunchKernelGGL(gemm_k, dim3(ntok / BM), dim3(512), NST * STB, stream,
                       mh, img, zbuf);
    hipLaunchKernelGGL(epi_k, dim3(ntok / 32), dim3(256), 0, stream,
                       zbuf, br, bn, eps, out_probs, out_idx, cnt, list);
    hipLaunchKernelGGL(refine_fp64, dim3(1024), dim3(256), 0, stream,
                       mh, Wr, br, Wn, bn, eps, out_probs, out_idx, cnt, list);
}

// Round 20
// 190.295 us; speedup vs baseline: 3.4436x; 1.1328x over previous
//
#include <hip/hip_runtime.h>
#include <math.h>

#define D_DIM 4096
#define E_DIM 64
#define KTOP 8
#define TAU 2e-4f     // ambiguity threshold: ~33 sigma of split-bf16 GEMM error (~6e-6 RMS)
#define BM 32         // tokens per gemm block; 256 thr, grid 512 -> 2 blocks/CU
#define NTS 64        // k-sections of 64 (each = two 32-k image tiles)
#define STB 40960     // bytes per pipeline stage: B 32KB + A 8KB
#define NST 2         // pipeline stages (80KB LDS -> 2 blocks/CU)

// workspace layout (bytes)
#define WS_LIST 1024
#define WS_IMG 66560              // 1024 + 64KB list; 16B aligned
#define WS_Z   (WS_IMG + 2097152) // after 2MB image: zbuf [16384][128] fp32 = 8MB

typedef __attribute__((ext_vector_type(8))) short bf16x8;
typedef __attribute__((ext_vector_type(4))) float f32x4;

#define MFMA(a, b, c) __builtin_amdgcn_mfma_f32_16x16x32_bf16(a, b, c, 0, 0, 0)

typedef const __attribute__((address_space(1))) void gas_void;
typedef __attribute__((address_space(3))) void las_void;
#define GLL16(src, dst) \
    __builtin_amdgcn_global_load_lds((gas_void*)(src), (las_void*)(dst), 16, 0, 0)
#define SCHED_FENCE() __builtin_amdgcn_sched_barrier(0)

// ---- split 8 fp32 -> hi/lo bf16x8 via v_cvt_pk_bf16_f32 (RNE) ----
__device__ inline void split8(float4 p, float4 q, bf16x8& h8, bf16x8& l8) {
    float xx[8] = {p.x, p.y, p.z, p.w, q.x, q.y, q.z, q.w};
    union { unsigned int w[4]; bf16x8 v; } H, L;
    #pragma unroll
    for (int i = 0; i < 4; ++i) {
        float a = xx[2 * i], b = xx[2 * i + 1];
        unsigned int hw;
        asm("v_cvt_pk_bf16_f32 %0, %1, %2" : "=v"(hw) : "v"(a), "v"(b));
        float ha = __uint_as_float(hw << 16);
        float hb = __uint_as_float(hw & 0xFFFF0000u);
        float ra = a - ha, rb = b - hb;           // exact residuals
        unsigned int lw;
        asm("v_cvt_pk_bf16_f32 %0, %1, %2" : "=v"(lw) : "v"(ra), "v"(rb));
        H.w[i] = hw; L.w[i] = lw;
    }
    h8 = H.v; l8 = L.v;
}

// ---- preconvert weights: Wr||Wn -> hi/lo bf16 image, fragment-linear per 32-k tile ----
__global__ __launch_bounds__(256)
void preconv(const float* __restrict__ Wr, const float* __restrict__ Wn,
             unsigned short* __restrict__ img, unsigned int* __restrict__ cnt)
{
    if (blockIdx.x == 0 && threadIdx.x == 0) *cnt = 0u;   // fused zero_cnt
    int t = blockIdx.x * 256 + threadIdx.x;      // 0..65535
    int kt = t >> 9, rem = t & 511;
    int koff = rem >> 7, col = rem & 127;
    int k = kt * 32 + koff * 8;
    const float* base = (col < E_DIM) ? (Wr + (size_t)col * D_DIM)
                                      : (Wn + (size_t)(col - E_DIM) * D_DIM);
    float4 x0 = *(const float4*)(base + k);
    float4 x1 = *(const float4*)(base + k + 4);
    bf16x8 h8, l8;
    split8(x0, x1, h8, l8);
    size_t o = (size_t)kt * 8192 + koff * 1024 + col * 8;
    *(bf16x8*)(img + o) = h8;
    *(bf16x8*)(img + o + 4096) = l8;
}

// ---- phase 1: split-bf16 MFMA GEMM -> zbuf ----
// BM=32, 256 thr (4 waves = 2 rowgroups x 2 colgroups), NST=2, 80KB LDS ->
// 2 blocks/CU = 2 independent barrier domains (r19 post-mortem: 1-block/CU
// lockstep serializes LDS/VALU/MFMA phases; second domain fills the stalls).
// A staging: swizzled-coalesced (r19, rule #21 both-sides involution).
__global__ __launch_bounds__(256)
void gemm_k(const float* __restrict__ mh,
            const unsigned short* __restrict__ Wimg,
            float* __restrict__ zbuf)
{
    extern __shared__ char smem[];       // NST*STB = 80KB dynamic

    const int tid  = threadIdx.x;
    const int lane = tid & 63;
    const int wv   = tid >> 6;       // 0..3
    const int wr   = wv >> 1;        // rowgroup 0..1 (16 tokens each)
    const int wc   = wv & 1;         // colgroup 0..1 (64 cols each)
    const int tok0 = blockIdx.x * BM;
    const int rloc = lane & 15;
    const int koff = lane >> 4;      // 0..3
    const int row  = wr * 16 + rloc; // 0..31
    const int rsw  = row & 15;       // read-side swizzle key

    int boff[4];
    #pragma unroll
    for (int fc = 0; fc < 4; ++fc)
        boff[fc] = koff * 1024 + (wc * 64 + fc * 16 + rloc) * 8;   // ushort idx

    const int4* gimg = (const int4*)Wimg;   // 2048 int4 per 64-k section

    // A staging source (swizzled, coalesced): slot tid <- (tok=tid>>4, kq);
    // slot tid+256 <- (tok+16, same kq) [(tid+256)>>4 & 15 unchanged]
    const int a_tok = tid >> 4;                       // 0..15
    const int a_kq  = (tid & 15) ^ (a_tok & 15);
    const float* asrc0 = mh + (size_t)(tok0 + a_tok) * D_DIM + a_kq * 4;
    const float* asrc1 = mh + (size_t)(tok0 + a_tok + 16) * D_DIM + a_kq * 4;

    f32x4 acc[4];
    #pragma unroll
    for (int fc = 0; fc < 4; ++fc) acc[fc] = {0.f, 0.f, 0.f, 0.f};

    auto stage_issue = [&](int t) {
        char* sb = smem + (t & 1) * STB;
        const int4* gB = gimg + (size_t)t * 2048 + tid;
        int4* dB = (int4*)sb + tid;
        GLL16(gB, dB);
        GLL16(gB + 256,  dB + 256);
        GLL16(gB + 512,  dB + 512);
        GLL16(gB + 768,  dB + 768);
        GLL16(gB + 1024, dB + 1024);
        GLL16(gB + 1280, dB + 1280);
        GLL16(gB + 1536, dB + 1536);
        GLL16(gB + 1792, dB + 1792);
        int4* dA = (int4*)(sb + 32768) + tid;
        GLL16(asrc0 + t * 64, dA);
        GLL16(asrc1 + t * 64, dA + 256);
    };

    stage_issue(0);
    SCHED_FENCE();
    asm volatile("s_waitcnt vmcnt(0)" ::: "memory");
    SCHED_FENCE();
    __builtin_amdgcn_s_barrier();
    SCHED_FENCE();

    for (int kt = 0; kt < NTS; ++kt) {
        if (kt + 1 < NTS) stage_issue(kt + 1);   // into buf^1
        SCHED_FENCE();
        {
            const char* sb = smem + (kt & 1) * STB;
            const unsigned short* Bst = (const unsigned short*)sb;
            const char* sa = sb + 32768;   // A: 512 granules [tok][kq^(tok&15)]
            #pragma unroll
            for (int s = 0; s < 2; ++s) {
                const int kf = s * 8 + 2 * koff;
                float4 f0 = *(const float4*)(sa + (row * 16 + ((kf)     ^ rsw)) * 16);
                float4 f1 = *(const float4*)(sa + (row * 16 + ((kf + 1) ^ rsw)) * 16);
                bf16x8 ah, al;
                split8(f0, f1, ah, al);
                const unsigned short* bb = Bst + s * 8192;
                #pragma unroll
                for (int fc = 0; fc < 4; ++fc) {
                    bf16x8 bh = *(const bf16x8*)(bb + boff[fc]);
                    bf16x8 bl = *(const bf16x8*)(bb + 4096 + boff[fc]);
                    acc[fc] = MFMA(ah, bh, acc[fc]);
                    acc[fc] = MFMA(al, bh, acc[fc]);
                    acc[fc] = MFMA(ah, bl, acc[fc]);
                }
            }
        }
        SCHED_FENCE();
        asm volatile("s_waitcnt vmcnt(0) lgkmcnt(0)" ::: "memory");
        SCHED_FENCE();
        __builtin_amdgcn_s_barrier();
        SCHED_FENCE();
    }

    // C-write: zbuf[tok][col], C-layout col=lane&15, row=(lane>>4)*4+reg (m89)
    float* zb = zbuf + (size_t)tok0 * 128;
    #pragma unroll
    for (int fc = 0; fc < 4; ++fc) {
        const int col = wc * 64 + fc * 16 + rloc;
        #pragma unroll
        for (int rg = 0; rg < 4; ++rg) {
            const int r = wr * 16 + koff * 4 + rg;
            zb[r * 128 + col] = acc[fc][rg];
        }
    }
}

// ---- phase 2: thread-per-token epilogue (NO cross-lane ops) ----
// r19 post-mortem: butterfly top-9 = dependent ds_bpermute chain, ~48us.
// New: 64-thr blocks, token = lane; branchless 9-deep insertion sort in
// NAMED scalars (rule #20); ties -> lower index (matches lax.top_k).
#define ISTEP(K) { bool gt = cv > v##K; \
    float tv = gt ? cv : v##K; int ti = gt ? ci : j##K; \
    float sv = gt ? v##K : cv; int si = gt ? j##K : ci; \
    v##K = tv; j##K = ti; cv = sv; ci = si; }

__global__ __launch_bounds__(64)
void epi_k(const float* __restrict__ zbuf,
           const float* __restrict__ br, const float* __restrict__ bn,
           const float* __restrict__ eps,
           float* __restrict__ out_probs, float* __restrict__ out_idx,
           unsigned int* __restrict__ cnt, int* __restrict__ list)
{
    __shared__ float ns[64 * 65];   // [tok][65] noisy logits (pad -> (t+e)%32 banks)
    __shared__ float ps[64 * 65];   // [tok][65] probs
    const int tid  = threadIdx.x;   // 0..63
    const int tok0 = blockIdx.x * 64;

    // phase A: coalesced stage + noisy-logit compute (16 quads/thread)
    for (int i = tid; i < 1024; i += 64) {
        const int t = i >> 4, q = i & 15;
        const float* zb = zbuf + (size_t)(tok0 + t) * 128 + q * 4;
        float4 zr4 = *(const float4*)zb;
        float4 zn4 = *(const float4*)(zb + 64);
        float4 ep4 = *(const float4*)(eps + (size_t)(tok0 + t) * E_DIM + q * 4);
        float4 br4 = *(const float4*)(br + q * 4);
        float4 bn4 = *(const float4*)(bn + q * 4);
        float zr[4] = {zr4.x, zr4.y, zr4.z, zr4.w};
        float zn[4] = {zn4.x, zn4.y, zn4.z, zn4.w};
        float ep[4] = {ep4.x, ep4.y, ep4.z, ep4.w};
        float bb[4] = {br4.x, br4.y, br4.z, br4.w};
        float cc[4] = {bn4.x, bn4.y, bn4.z, bn4.w};
        #pragma unroll
        for (int j = 0; j < 4; ++j) {
            float n = zn[j] + cc[j];
            float sp = fmaxf(n, 0.f) + log1pf(expf(-fabsf(n)));
            ns[t * 65 + q * 4 + j] = (zr[j] + bb[j]) + ep[j] * sp;
        }
    }
    __syncthreads();

    // phase B: per-thread top-9 insertion sort over 64 experts
    float v0 = -INFINITY, v1 = -INFINITY, v2 = -INFINITY, v3 = -INFINITY,
          v4 = -INFINITY, v5 = -INFINITY, v6 = -INFINITY, v7 = -INFINITY,
          v8 = -INFINITY;
    int j0 = 0, j1 = 0, j2 = 0, j3 = 0, j4 = 0, j5 = 0, j6 = 0, j7 = 0, j8 = 0;
    const float* nrow = ns + tid * 65;
    for (int e = 0; e < 64; ++e) {
        float cv = nrow[e]; int ci = e;
        ISTEP(0) ISTEP(1) ISTEP(2) ISTEP(3) ISTEP(4)
        ISTEP(5) ISTEP(6) ISTEP(7) ISTEP(8)
    }
    const float m0 = v0;
    float denom = expf(v0 - m0) + expf(v1 - m0) + expf(v2 - m0) + expf(v3 - m0)
                + expf(v4 - m0) + expf(v5 - m0) + expf(v6 - m0) + expf(v7 - m0);
    float mingap = fminf(fminf(fminf(v0 - v1, v1 - v2), fminf(v2 - v3, v3 - v4)),
                         fminf(fminf(v4 - v5, v5 - v6), fminf(v6 - v7, v7 - v8)));

    // phase C: zero probs row, scatter 8, write out
    float* prow = ps + tid * 65;
    #pragma unroll 8
    for (int e = 0; e < 64; ++e) prow[e] = 0.f;
    prow[j0] = expf(v0 - m0) / denom;
    prow[j1] = expf(v1 - m0) / denom;
    prow[j2] = expf(v2 - m0) / denom;
    prow[j3] = expf(v3 - m0) / denom;
    prow[j4] = expf(v4 - m0) / denom;
    prow[j5] = expf(v5 - m0) / denom;
    prow[j6] = expf(v6 - m0) / denom;
    prow[j7] = expf(v7 - m0) / denom;
    __syncthreads();

    for (int i = tid; i < 4096; i += 64) {
        const int t = i >> 6, e = i & 63;
        out_probs[(size_t)(tok0 + t) * E_DIM + e] = ps[t * 65 + e];
    }
    {
        const size_t tg = (size_t)(tok0 + tid);
        float* oi = out_idx + tg * KTOP;
        oi[0] = (float)j0; oi[1] = (float)j1; oi[2] = (float)j2; oi[3] = (float)j3;
        oi[4] = (float)j4; oi[5] = (float)j5; oi[6] = (float)j6; oi[7] = (float)j7;
        if (mingap < TAU) {
            unsigned int wpos = atomicAdd(cnt, 1u);
            list[wpos] = (int)tg;
        }
    }
}

// ---- fp64 exact recompute for flagged tokens: 1 block/token ----
__global__ __launch_bounds__(256)
void refine_fp64(const float* __restrict__ mh,
                 const float* __restrict__ Wr, const float* __restrict__ br,
                 const float* __restrict__ Wn, const float* __restrict__ bn,
                 const float* __restrict__ eps,
                 float* __restrict__ out_probs, float* __restrict__ out_idx,
                 const unsigned int* __restrict__ cnt, const int* __restrict__ list)
{
    __shared__ double red[128];
    const unsigned int n = *cnt;
    const int tid  = threadIdx.x;
    const int lane = tid & 63;
    const int wv   = tid >> 6;     // 0..3

    for (unsigned int i = blockIdx.x; i < n; i += gridDim.x) {
        const int tok = list[i];
        const float* xb = mh + (size_t)tok * D_DIM;

        for (int r = 0; r < 32; ++r) {
            const int rrow = wv * 32 + r;
            const float* wp = (rrow < E_DIM) ? (Wr + (size_t)rrow * D_DIM)
                                             : (Wn + (size_t)(rrow - E_DIM) * D_DIM);
            double s0 = 0.0, s1 = 0.0, s2 = 0.0, s3 = 0.0;
            #pragma unroll 4
            for (int k = lane * 4; k < D_DIM; k += 256) {
                float4 xv = *(const float4*)(xb + k);
                float4 w4 = *(const float4*)(wp + k);
                s0 += (double)xv.x * (double)w4.x;
                s1 += (double)xv.y * (double)w4.y;
                s2 += (double)xv.z * (double)w4.z;
                s3 += (double)xv.w * (double)w4.w;
            }
            double s = (s0 + s1) + (s2 + s3);
            #pragma unroll
            for (int off = 32; off > 0; off >>= 1) s += __shfl_xor(s, off);
            if (lane == 0) red[rrow] = s;
        }
        __syncthreads();

        if (wv == 0) {   // epilogue: lane = expert
            double zr = red[lane] + (double)br[lane];
            double zn = red[E_DIM + lane] + (double)bn[lane];
            double sp = fmax(zn, 0.0) + log1p(exp(-fabs(zn)));
            double nl = zr + (double)eps[(size_t)tok * E_DIM + lane] * sp;
            double v = nl, m0 = 0.0, denom = 0.0;
            bool selected = false;
            int rankedIdx = 0;
            #pragma unroll
            for (int k = 0; k < KTOP; ++k) {
                double mv = v; int mi = lane;
                #pragma unroll
                for (int off = 32; off > 0; off >>= 1) {
                    double ov = __shfl_xor(mv, off);
                    int    oi = __shfl_xor(mi, off);
                    if (ov > mv || (ov == mv && oi < mi)) { mv = ov; mi = oi; }
                }
                if (k == 0) m0 = mv;
                denom += exp(mv - m0);
                if (lane == mi) { selected = true; v = -INFINITY; }
                if (lane == k) rankedIdx = mi;
            }
            float p = selected ? (float)(exp(nl - m0) / denom) : 0.f;
            out_probs[(size_t)tok * E_DIM + lane] = p;
            if (lane < KTOP) out_idx[(size_t)tok * KTOP + lane] = (float)rankedIdx;
        }
        __syncthreads();   // red reused next iteration
    }
}

extern "C" void kernel_launch(void* const* d_in, const int* in_sizes, int n_in,
                              void* d_out, int out_size, void* d_ws, size_t ws_size,
                              hipStream_t stream) {
    const float* mh  = (const float*)d_in[0];
    const float* Wr  = (const float*)d_in[1];
    const float* br  = (const float*)d_in[2];
    const float* Wn  = (const float*)d_in[3];
    const float* bn  = (const float*)d_in[4];
    const float* eps = (const float*)d_in[5];

    const int ntok = in_sizes[0] / D_DIM;                     // 16384
    float* out_probs = (float*)d_out;                         // [ntok][64]
    float* out_idx   = (float*)d_out + (size_t)ntok * E_DIM;  // [ntok][8] as float

    unsigned int* cnt = (unsigned int*)d_ws;
    int* list = (int*)((char*)d_ws + WS_LIST);
    unsigned short* img = (unsigned short*)((char*)d_ws + WS_IMG);
    float* zbuf = (float*)((char*)d_ws + WS_Z);

    hipLaunchKernelGGL(preconv, dim3(256), dim3(256), 0, stream, Wr, Wn, img, cnt);
    hipLaunchKernelGGL(gemm_k, dim3(ntok / BM), dim3(256), NST * STB, stream,
                       mh, img, zbuf);
    hipLaunchKernelGGL(epi_k, dim3(ntok / 64), dim3(64), 0, stream,
                       zbuf, br, bn, eps, out_probs, out_idx, cnt, list);
    hipLaunchKernelGGL(refine_fp64, dim3(1024), dim3(256), 0, stream,
                       mh, Wr, br, Wn, bn, eps, out_probs, out_idx, cnt, list);
}